// Round 6
// baseline (219.272 us; speedup 1.0000x reference)
//
#include <hip/hip_runtime.h>
#include <hip/hip_bf16.h>
#include <math.h>

#define NN 20000
#define EF 720000

typedef float  f4 __attribute__((ext_vector_type(4)));
typedef unsigned int u4 __attribute__((ext_vector_type(4)));

__device__ __forceinline__ void MFMA(f4& c, u4 a, u4 b) {
    asm("v_mfma_f32_16x16x32_bf16 %0, %1, %2, %0" : "+v"(c) : "v"(a), "v"(b));
}

__device__ __forceinline__ unsigned pk(float a, float b) {
    __hip_bfloat162 t = __halves2bfloat162(__float2bfloat16(a), __float2bfloat16(b));
    unsigned u; __builtin_memcpy(&u, &t, 4); return u;
}
__device__ __forceinline__ float bf2f(unsigned short u) {
    return __builtin_bit_cast(float, (unsigned)u << 16);
}
__device__ __forceinline__ f4 bf2f4(ushort4 u) {
    f4 r; r.x = bf2f(u.x); r.y = bf2f(u.y); r.z = bf2f(u.z); r.w = bf2f(u.w); return r;
}
__device__ __forceinline__ float dot4(f4 a, f4 b) {
    return a.x * b.x + a.y * b.y + a.z * b.z + a.w * b.w;
}
__device__ __forceinline__ void fma4(f4& acc, float w, f4 v) {
    acc.x += w * v.x; acc.y += w * v.y; acc.z += w * v.z; acc.w += w * v.w;
}

// ---------------------------------------------------------------- prep: bf16 weights + transposes
__global__ __launch_bounds__(256) void k_prep(
    const float* __restrict__ mw1, const float* __restrict__ mb1,
    const float* __restrict__ mw2, const float* __restrict__ mw3,
    const float* __restrict__ hw1, const float* __restrict__ hw2, const float* __restrict__ hw3,
    const float* __restrict__ we,
    __hip_bfloat16* __restrict__ W1b, __hip_bfloat16* __restrict__ W2b, __hip_bfloat16* __restrict__ W3b,
    __hip_bfloat16* __restrict__ H1b, __hip_bfloat16* __restrict__ H2b, __hip_bfloat16* __restrict__ H3b,
    float* __restrict__ weT)
{
    int t = blockIdx.x * 256 + threadIdx.x;
    if (t < 2048) {  // W1b[ch][k], K=32: k<21 weights, k==21 bias, rest 0
        int ch = t >> 5, k = t & 31;
        float v = (k < 21) ? mw1[k * 64 + ch] : (k == 21 ? mb1[ch] : 0.f);
        W1b[t] = __float2bfloat16(v); return;
    }
    t -= 2048;
    if (t < 4096) { int ch = t >> 6, k = t & 63; W2b[t] = __float2bfloat16(mw2[k * 64 + ch]); return; }
    t -= 4096;
    if (t < 4096) { int ch = t >> 6, k = t & 63; W3b[t] = __float2bfloat16(mw3[k * 64 + ch]); return; }
    t -= 4096;
    if (t < 4096) { int ch = t >> 6, k = t & 63; H1b[t] = __float2bfloat16(hw1[k * 64 + ch]); return; }
    t -= 4096;
    if (t < 4096) { int ch = t >> 6, k = t & 63; H2b[t] = __float2bfloat16(hw2[k * 64 + ch]); return; }
    t -= 4096;
    if (t < 2048) {  // H3b padded to 32 rows
        int ch = t >> 6, k = t & 63;
        float v = (ch < 20) ? hw3[k * 20 + ch] : 0.f;
        H3b[t] = __float2bfloat16(v); return;
    }
    t -= 2048;
    if (t < 10752) { int cf = t / 84, a = t % 84; weT[t] = we[a * 128 + cf]; return; }
}

// ---------------------------------------------------------------- CSR via binary search
__global__ __launch_bounds__(256) void k_csr(
    const int* __restrict__ dst, const float* __restrict__ mask, int* __restrict__ row_off)
{
    int n = blockIdx.x * 256 + threadIdx.x;
    if (n > NN) return;
    int lo = 0, hi = EF;
    while (lo < hi) { int mid = (lo + hi) >> 1; if (mask[mid] > 0.5f) lo = mid + 1; else hi = mid; }
    int Ea = lo;
    lo = 0; hi = Ea;
    while (lo < hi) { int mid = (lo + hi) >> 1; if (dst[mid] < n) lo = mid + 1; else hi = mid; }
    row_off[n] = lo;
}

// ---------------------------------------------------------------- node features + projections
// selffb[n][32] bf16: [0..19]=self_feat, [20]=1.0 (bias slot), rest 0
// qkp[n][64] f32: [h*32+a] = sum_c q_h[c]*wk[a][h*64+c] for a<20; [h*32+20] = bk_h.q_h; rest 0
__global__ __launch_bounds__(256) void k_node(
    const float* __restrict__ angle, const float* __restrict__ mol, const float* __restrict__ gen,
    const int* __restrict__ row_off,
    const float* __restrict__ wq, const float* __restrict__ bq,
    const float* __restrict__ wk, const float* __restrict__ bk,
    const float* __restrict__ wskip, const float* __restrict__ bskip,
    const float* __restrict__ weT,
    float* __restrict__ selff, __hip_bfloat16* __restrict__ selffb,
    float* __restrict__ qf, float* __restrict__ skipf,
    float* __restrict__ qwe, float* __restrict__ qkp)
{
    __shared__ float qlds[4 * 128];
    int wid = threadIdx.x >> 6, lane = threadIdx.x & 63;
    int n = blockIdx.x * 4 + wid;

    float an = angle[n];
    float sv, cv; sincosf(an, &sv, &cv);
    float degf = (float)(row_off[n + 1] - row_off[n]);
    float sf[20];
    sf[0] = sv; sf[1] = cv;
#pragma unroll
    for (int j = 0; j < 16; j++) sf[2 + j] = mol[n * 16 + j];
    sf[18] = gen[n];
    sf[19] = degf;

    float sval = (lane == 0) ? sv : (lane == 1) ? cv :
                 (lane < 18) ? mol[n * 16 + (lane - 2)] :
                 (lane == 18) ? gen[n] : degf;
    if (lane < 20) selff[n * 20 + lane] = sval;
    if (lane < 32) {
        float v = (lane < 20) ? sval : (lane == 20 ? 1.f : 0.f);
        selffb[n * 32 + lane] = __float2bfloat16(v);
    }

    float q0 = bq[lane], q1 = bq[64 + lane];
    float sk = bskip[lane];
#pragma unroll
    for (int a = 0; a < 20; a++) {
        float s = sf[a];
        q0 += s * wq[a * 128 + lane];  q1 += s * wq[a * 128 + 64 + lane];
        sk += s * wskip[a * 64 + lane];
    }
    qf[n * 128 + lane] = q0; qf[n * 128 + 64 + lane] = q1;
    skipf[n * 64 + lane] = sk;
    qlds[wid * 128 + lane] = q0; qlds[wid * 128 + 64 + lane] = q1;

    // bias_h = bk_h . q_h (wave reduce)
    float b0 = q0 * bk[lane];
    float b1 = q1 * bk[64 + lane];
#pragma unroll
    for (int mk = 1; mk < 64; mk <<= 1) {
        b0 += __shfl_xor(b0, mk, 64);
        b1 += __shfl_xor(b1, mk, 64);
    }
    __syncthreads();

    // qwe[n][h][a] = sum_c q[h][c] * we[a][h*64+c]
#pragma unroll
    for (int r = 0; r < 3; r++) {
        int o = r * 64 + lane;
        if (o < 168) {
            int h = (o >= 84) ? 1 : 0;
            int a = o - 84 * h;
            float acc = 0.f, acc2 = 0.f;
#pragma unroll
            for (int c = 0; c < 64; c += 2) {
                acc  += qlds[wid * 128 + h * 64 + c]     * weT[(h * 64 + c) * 84 + a];
                acc2 += qlds[wid * 128 + h * 64 + c + 1] * weT[(h * 64 + c + 1) * 84 + a];
            }
            qwe[n * 168 + o] = acc + acc2;
        }
    }

    // qk projection
    {
        int h = lane >> 5, a = lane & 31;
        float val;
        if (a < 20) {
            float acc = 0.f, acc2 = 0.f;
#pragma unroll
            for (int c = 0; c < 64; c += 2) {
                acc  += qlds[wid * 128 + h * 64 + c]     * wk[a * 128 + h * 64 + c];
                acc2 += qlds[wid * 128 + h * 64 + c + 1] * wk[a * 128 + h * 64 + c + 1];
            }
            val = acc + acc2;
        } else if (a == 20) {
            val = h ? b1 : b0;
        } else {
            val = 0.f;
        }
        qkp[n * 64 + h * 32 + a] = val;
    }
}

// ---------------------------------------------------------------- edge MLP via MFMA (wave = 64 edges, 4 waves/block)
__device__ __forceinline__ void write_tiles(char* lds, int l, f4 (&acc)[4][4], const float* bias)
{
#pragma unroll
    for (int m = 0; m < 4; m++) {
        f4 bv;
        if (bias) bv = *(const f4*)(bias + m * 16 + ((l >> 4) << 2));
        else      { bv.x = 0.f; bv.y = 0.f; bv.z = 0.f; bv.w = 0.f; }
#pragma unroll
        for (int n = 0; n < 4; n++) {
            f4 v = acc[m][n];
            float v0 = fmaxf(v.x + bv.x, 0.f);
            float v1 = fmaxf(v.y + bv.y, 0.f);
            float v2 = fmaxf(v.z + bv.z, 0.f);
            float v3 = fmaxf(v.w + bv.w, 0.f);
            int e   = n * 16 + (l & 15);
            int ch0 = m * 16 + ((l >> 4) << 2);
            int byte = e * 128 + ((((ch0 >> 3) ^ (e & 7))) << 4) + (ch0 & 7) * 2;
            uint2 w; w.x = pk(v0, v1); w.y = pk(v2, v3);
            *(uint2*)(lds + byte) = w;
        }
    }
}

__global__ __launch_bounds__(256) void k_edge_mfma(
    const float* __restrict__ x, const float* __restrict__ angle, const float* __restrict__ mol,
    const int* __restrict__ src, const int* __restrict__ dst,
    const __hip_bfloat16* __restrict__ W1b, const __hip_bfloat16* __restrict__ W2b,
    const __hip_bfloat16* __restrict__ W3b,
    const float* __restrict__ mb2, const float* __restrict__ mb3,
    __hip_bfloat16* __restrict__ msg)
{
    __shared__ char lds_all[4][64 * 128];
    int wv = threadIdx.x >> 6, l = threadIdx.x & 63;
    char* lds = lds_all[wv];
    int e0 = (blockIdx.x * 4 + wv) * 64;
    if (e0 + 64 > EF) e0 = EF - 64;

    int s = src[e0 + l], d = dst[e0 + l];
    float2 xs = ((const float2*)x)[s], xd = ((const float2*)x)[d];
    float dx = xs.x - xd.x, dy = xs.y - xd.y;
    float r = sqrtf(fmaxf(dx * dx + dy * dy, 1e-12f));
    float da = angle[s] - angle[d];
    float sv, cv; sincosf(da, &sv, &cv);
    const float4* m4 = (const float4*)mol;
    float4 sa = m4[s * 4 + 0], sb = m4[s * 4 + 1], sc = m4[s * 4 + 2], sd = m4[s * 4 + 3];
    float4 ta = m4[d * 4 + 0], tb = m4[d * 4 + 1], tc = m4[d * 4 + 2], td = m4[d * 4 + 3];
    float f[22];
    f[0] = dx; f[1] = dy; f[2] = r; f[3] = sv; f[4] = cv;
    f[5]  = sa.x - ta.x; f[6]  = sa.y - ta.y; f[7]  = sa.z - ta.z; f[8]  = sa.w - ta.w;
    f[9]  = sb.x - tb.x; f[10] = sb.y - tb.y; f[11] = sb.z - tb.z; f[12] = sb.w - tb.w;
    f[13] = sc.x - tc.x; f[14] = sc.y - tc.y; f[15] = sc.z - tc.z; f[16] = sc.w - tc.w;
    f[17] = sd.x - td.x; f[18] = sd.y - td.y; f[19] = sd.z - td.z; f[20] = sd.w - td.w;
    f[21] = 1.f;
    unsigned p[16];
#pragma unroll
    for (int j = 0; j < 11; j++) p[j] = pk(f[2 * j], f[2 * j + 1]);
#pragma unroll
    for (int j = 11; j < 16; j++) p[j] = 0u;
#pragma unroll
    for (int g = 0; g < 4; g++) {
        int byte = l * 64 + ((g ^ (l & 3)) << 4);
        u4 w; w.x = p[4 * g]; w.y = p[4 * g + 1]; w.z = p[4 * g + 2]; w.w = p[4 * g + 3];
        *(u4*)(lds + byte) = w;
    }
    __syncthreads();

    u4 B1[4];
#pragma unroll
    for (int n = 0; n < 4; n++) {
        int e = n * 16 + (l & 15);
        int byte = e * 64 + ((((l >> 4) & 3) ^ (e & 3)) << 4);
        B1[n] = *(const u4*)(lds + byte);
    }
    __syncthreads();

    f4 acc[4][4];
#pragma unroll
    for (int m = 0; m < 4; m++)
#pragma unroll
        for (int n = 0; n < 4; n++) { acc[m][n].x = 0.f; acc[m][n].y = 0.f; acc[m][n].z = 0.f; acc[m][n].w = 0.f; }

    const unsigned short* W1u = (const unsigned short*)W1b;
    const unsigned short* W2u = (const unsigned short*)W2b;
    const unsigned short* W3u = (const unsigned short*)W3b;
#pragma unroll
    for (int m = 0; m < 4; m++) {
        u4 w = *(const u4*)(W1u + (m * 16 + (l & 15)) * 32 + (l >> 4) * 8);
#pragma unroll
        for (int n = 0; n < 4; n++) MFMA(acc[m][n], w, B1[n]);
    }
    write_tiles(lds, l, acc, nullptr);
    __syncthreads();

    u4 B2[4][2];
#pragma unroll
    for (int n = 0; n < 4; n++)
#pragma unroll
        for (int ks = 0; ks < 2; ks++) {
            int e = n * 16 + (l & 15);
            int g = ks * 4 + (l >> 4);
            B2[n][ks] = *(const u4*)(lds + e * 128 + ((g ^ (e & 7)) << 4));
        }
    __syncthreads();
#pragma unroll
    for (int m = 0; m < 4; m++)
#pragma unroll
        for (int n = 0; n < 4; n++) { acc[m][n].x = 0.f; acc[m][n].y = 0.f; acc[m][n].z = 0.f; acc[m][n].w = 0.f; }
#pragma unroll
    for (int m = 0; m < 4; m++)
#pragma unroll
        for (int ks = 0; ks < 2; ks++) {
            u4 w = *(const u4*)(W2u + (m * 16 + (l & 15)) * 64 + ks * 32 + (l >> 4) * 8);
#pragma unroll
            for (int n = 0; n < 4; n++) MFMA(acc[m][n], w, B2[n][ks]);
        }
    write_tiles(lds, l, acc, mb2);
    __syncthreads();

#pragma unroll
    for (int n = 0; n < 4; n++)
#pragma unroll
        for (int ks = 0; ks < 2; ks++) {
            int e = n * 16 + (l & 15);
            int g = ks * 4 + (l >> 4);
            B2[n][ks] = *(const u4*)(lds + e * 128 + ((g ^ (e & 7)) << 4));
        }
    __syncthreads();
#pragma unroll
    for (int m = 0; m < 4; m++)
#pragma unroll
        for (int n = 0; n < 4; n++) { acc[m][n].x = 0.f; acc[m][n].y = 0.f; acc[m][n].z = 0.f; acc[m][n].w = 0.f; }
#pragma unroll
    for (int m = 0; m < 4; m++)
#pragma unroll
        for (int ks = 0; ks < 2; ks++) {
            u4 w = *(const u4*)(W3u + (m * 16 + (l & 15)) * 64 + ks * 32 + (l >> 4) * 8);
#pragma unroll
            for (int n = 0; n < 4; n++) MFMA(acc[m][n], w, B2[n][ks]);
        }
    write_tiles(lds, l, acc, mb3);
    __syncthreads();

#pragma unroll
    for (int it = 0; it < 8; it++) {
        int e = it * 8 + (l >> 3);
        int g = l & 7;
        u4 vv = *(const u4*)(lds + e * 128 + ((g ^ (e & 7)) << 4));
        *(u4*)((unsigned short*)msg + (size_t)(e0 + e) * 64 + g * 8) = vv;
    }
}

// ---------------------------------------------------------------- attention aggregate
// wave = node; 4 edge-groups of 16 lanes. Per edge gather: msg (128B) + selffb (64B).
__global__ __launch_bounds__(256) void k_attn(
    const int* __restrict__ row_off, const int* __restrict__ src,
    const __hip_bfloat16* __restrict__ msg,
    const __hip_bfloat16* __restrict__ selffb, const float* __restrict__ qkp,
    const float* __restrict__ qwe, const float* __restrict__ selff, const float* __restrict__ skipf,
    const float* __restrict__ we, const float* __restrict__ wv, const float* __restrict__ bv,
    float* __restrict__ outb)
{
    __shared__ float redm[4][2][64];
    __shared__ float reds[4][2][32];
    int tid = threadIdx.x, wid = tid >> 6, lane = tid & 63;
    int g = lane >> 4, c16 = lane & 15;
    int n = blockIdx.x * 4 + wid;

    f4 qm0 = *(const f4*)(qwe + n * 168 + 4 * c16);
    f4 qm1 = *(const f4*)(qwe + n * 168 + 84 + 4 * c16);
    float2 qk0 = *(const float2*)(qkp + n * 64 + 2 * c16);
    float2 qk1 = *(const float2*)(qkp + n * 64 + 32 + 2 * c16);

    float a00 = 0.f, a01 = 0.f;
#pragma unroll
    for (int j = 0; j < 20; j++) {
        float sfj = selff[n * 20 + j];
        a00 += sfj * qwe[n * 168 + 64 + j];
        a01 += sfj * qwe[n * 168 + 84 + 64 + j];
    }

    const unsigned short* msgu = (const unsigned short*)msg;
    const unsigned short* sfu  = (const unsigned short*)selffb;
    int r0 = row_off[n], r1 = row_off[n + 1];
    int nit = (r1 - r0 + 3) >> 2;

    f4 Wm0 = {0,0,0,0}, Wm1 = {0,0,0,0};
    float Ws00 = 0.f, Ws01 = 0.f, Ws10 = 0.f, Ws11 = 0.f;
    float S0 = 0.f, S1 = 0.f;

#pragma unroll 2
    for (int it = 0; it < nit; it++) {
        int e = r0 + it * 4 + g;
        bool ok = (e < r1);
        int ec = ok ? e : r0;
        int s = src[ec];
        ushort2 su = *(const ushort2*)(sfu + (size_t)s * 32 + 2 * c16);
        float sf0 = bf2f(su.x), sf1 = bf2f(su.y);
        f4 mc = bf2f4(*(const ushort4*)(msgu + (size_t)ec * 64 + 4 * c16));

        float t0 = dot4(qm0, mc) + sf0 * qk0.x + sf1 * qk0.y;
        float t1 = dot4(qm1, mc) + sf0 * qk1.x + sf1 * qk1.y;
#pragma unroll
        for (int mk = 1; mk < 16; mk <<= 1) {
            t0 += __shfl_xor(t0, mk, 64);
            t1 += __shfl_xor(t1, mk, 64);
        }
        float w0 = ok ? __expf((t0 + a00) * 0.125f) : 0.f;
        float w1 = ok ? __expf((t1 + a01) * 0.125f) : 0.f;
        S0 += w0; S1 += w1;
        fma4(Wm0, w0, mc); fma4(Wm1, w1, mc);
        Ws00 += w0 * sf0; Ws01 += w0 * sf1;
        Ws10 += w1 * sf0; Ws11 += w1 * sf1;
    }

    // cross-group reduce
#pragma unroll
    for (int mk = 16; mk <= 32; mk <<= 1) {
        Wm0.x += __shfl_xor(Wm0.x, mk, 64); Wm0.y += __shfl_xor(Wm0.y, mk, 64);
        Wm0.z += __shfl_xor(Wm0.z, mk, 64); Wm0.w += __shfl_xor(Wm0.w, mk, 64);
        Wm1.x += __shfl_xor(Wm1.x, mk, 64); Wm1.y += __shfl_xor(Wm1.y, mk, 64);
        Wm1.z += __shfl_xor(Wm1.z, mk, 64); Wm1.w += __shfl_xor(Wm1.w, mk, 64);
        Ws00 += __shfl_xor(Ws00, mk, 64); Ws01 += __shfl_xor(Ws01, mk, 64);
        Ws10 += __shfl_xor(Ws10, mk, 64); Ws11 += __shfl_xor(Ws11, mk, 64);
        S0 += __shfl_xor(S0, mk, 64); S1 += __shfl_xor(S1, mk, 64);
    }

    if (g == 0) {
        *(f4*)(&redm[wid][0][4 * c16]) = Wm0;
        *(f4*)(&redm[wid][1][4 * c16]) = Wm1;
        float2 s0; s0.x = Ws00; s0.y = Ws01;
        float2 s1; s1.x = Ws10; s1.y = Ws11;
        *(float2*)(&reds[wid][0][2 * c16]) = s0;
        *(float2*)(&reds[wid][1][2 * c16]) = s1;
    }
    // same-wave LDS write->read; lgkmcnt ordering handled by compiler (validated r2-r5).

    const float* wmA = &redm[wid][0][0];
    const float* wmB = &redm[wid][1][0];
    const float* wsA = &reds[wid][0][0];
    const float* wsB = &reds[wid][1][0];
    float acc0 = S0 * bv[lane], acc1 = S1 * bv[64 + lane];
#pragma unroll 4
    for (int a = 0; a < 64; a += 2) {
        acc0 += wmA[a] * we[a * 128 + lane]      + wmA[a + 1] * we[(a + 1) * 128 + lane];
        acc1 += wmB[a] * we[a * 128 + 64 + lane] + wmB[a + 1] * we[(a + 1) * 128 + 64 + lane];
    }
#pragma unroll
    for (int j = 0; j < 20; j++) {
        float sfj = selff[n * 20 + j];
        acc0 += S0 * sfj * we[(64 + j) * 128 + lane];
        acc1 += S1 * sfj * we[(64 + j) * 128 + 64 + lane];
    }
#pragma unroll 2
    for (int a = 0; a < 20; a += 2) {
        acc0 += wsA[a] * wv[a * 128 + lane]      + wsA[a + 1] * wv[(a + 1) * 128 + lane];
        acc1 += wsB[a] * wv[a * 128 + 64 + lane] + wsB[a + 1] * wv[(a + 1) * 128 + 64 + lane];
    }
    float o0 = acc0 / (S0 + 1e-16f);
    float o1 = acc1 / (S1 + 1e-16f);
    outb[n * 64 + lane] = 0.5f * (o0 + o1) + skipf[n * 64 + lane];
}

// ---------------------------------------------------------------- final MLP via MFMA (1 wave = 64 nodes)
__global__ __launch_bounds__(64) void k_final_mfma(
    const float* __restrict__ outb,
    const __hip_bfloat16* __restrict__ H1b, const __hip_bfloat16* __restrict__ H2b,
    const __hip_bfloat16* __restrict__ H3b,
    const float* __restrict__ hb1, const float* __restrict__ hb2, const float* __restrict__ hb3,
    float* __restrict__ out)
{
    __shared__ char lds[64 * 128];
    int l = threadIdx.x;
    int n0 = blockIdx.x * 64;
    int nl = n0 + l;
    int nn = (nl < NN) ? nl : (NN - 1);

    const float* row = outb + (size_t)nn * 64;
#pragma unroll
    for (int g = 0; g < 8; g++) {
        u4 w;
        w.x = pk(row[8 * g + 0], row[8 * g + 1]);
        w.y = pk(row[8 * g + 2], row[8 * g + 3]);
        w.z = pk(row[8 * g + 4], row[8 * g + 5]);
        w.w = pk(row[8 * g + 6], row[8 * g + 7]);
        *(u4*)(lds + l * 128 + ((g ^ (l & 7)) << 4)) = w;
    }
    __syncthreads();

    const unsigned short* H1u = (const unsigned short*)H1b;
    const unsigned short* H2u = (const unsigned short*)H2b;
    const unsigned short* H3u = (const unsigned short*)H3b;

    u4 B[4][2];
    f4 acc[4][4];

    // ---- stage 1
#pragma unroll
    for (int n = 0; n < 4; n++)
#pragma unroll
        for (int ks = 0; ks < 2; ks++) {
            int e = n * 16 + (l & 15);
            int g = ks * 4 + (l >> 4);
            B[n][ks] = *(const u4*)(lds + e * 128 + ((g ^ (e & 7)) << 4));
        }
    __syncthreads();
#pragma unroll
    for (int m = 0; m < 4; m++)
#pragma unroll
        for (int n = 0; n < 4; n++) { acc[m][n].x = 0.f; acc[m][n].y = 0.f; acc[m][n].z = 0.f; acc[m][n].w = 0.f; }
#pragma unroll
    for (int m = 0; m < 4; m++)
#pragma unroll
        for (int ks = 0; ks < 2; ks++) {
            u4 w = *(const u4*)(H1u + (m * 16 + (l & 15)) * 64 + ks * 32 + (l >> 4) * 8);
#pragma unroll
            for (int n = 0; n < 4; n++) MFMA(acc[m][n], w, B[n][ks]);
        }
    write_tiles(lds, l, acc, hb1);
    __syncthreads();

    // ---- stage 2
#pragma unroll
    for (int n = 0; n < 4; n++)
#pragma unroll
        for (int ks = 0; ks < 2; ks++) {
            int e = n * 16 + (l & 15);
            int g = ks * 4 + (l >> 4);
            B[n][ks] = *(const u4*)(lds + e * 128 + ((g ^ (e & 7)) << 4));
        }
    __syncthreads();
#pragma unroll
    for (int m = 0; m < 4; m++)
#pragma unroll
        for (int n = 0; n < 4; n++) { acc[m][n].x = 0.f; acc[m][n].y = 0.f; acc[m][n].z = 0.f; acc[m][n].w = 0.f; }
#pragma unroll
    for (int m = 0; m < 4; m++)
#pragma unroll
        for (int ks = 0; ks < 2; ks++) {
            u4 w = *(const u4*)(H2u + (m * 16 + (l & 15)) * 64 + ks * 32 + (l >> 4) * 8);
#pragma unroll
            for (int n = 0; n < 4; n++) MFMA(acc[m][n], w, B[n][ks]);
        }
    write_tiles(lds, l, acc, hb2);
    __syncthreads();

    // ---- stage 3: 64 -> 20
#pragma unroll
    for (int n = 0; n < 4; n++)
#pragma unroll
        for (int ks = 0; ks < 2; ks++) {
            int e = n * 16 + (l & 15);
            int g = ks * 4 + (l >> 4);
            B[n][ks] = *(const u4*)(lds + e * 128 + ((g ^ (e & 7)) << 4));
        }

    f4 acc3[2][4];
#pragma unroll
    for (int m = 0; m < 2; m++)
#pragma unroll
        for (int n = 0; n < 4; n++) { acc3[m][n].x = 0.f; acc3[m][n].y = 0.f; acc3[m][n].z = 0.f; acc3[m][n].w = 0.f; }
#pragma unroll
    for (int m = 0; m < 2; m++)
#pragma unroll
        for (int ks = 0; ks < 2; ks++) {
            u4 w = *(const u4*)(H3u + (m * 16 + (l & 15)) * 64 + ks * 32 + (l >> 4) * 8);
#pragma unroll
            for (int n = 0; n < 4; n++) MFMA(acc3[m][n], w, B[n][ks]);
        }

#pragma unroll
    for (int m = 0; m < 2; m++) {
#pragma unroll
        for (int j = 0; j < 4; j++) {
            int ch = m * 16 + (l >> 4) * 4 + j;
            if (ch < 20) {
                float b = hb3[ch];
#pragma unroll
                for (int nt = 0; nt < 4; nt++) {
                    int node = n0 + nt * 16 + (l & 15);
                    if (node < NN) {
                        float v = acc3[m][nt][j] + b;
                        if (ch < 2)       out[node * 2 + ch] = v;
                        else if (ch == 2) out[2 * NN + node] = v;
                        else if (ch < 19) out[3 * NN + node * 16 + (ch - 3)] = v;
                        else              out[19 * NN + node] = v;
                    }
                }
            }
        }
    }
}

// ---------------------------------------------------------------- launch
extern "C" void kernel_launch(void* const* d_in, const int* in_sizes, int n_in,
                              void* d_out, int out_size, void* d_ws, size_t ws_size,
                              hipStream_t stream)
{
    const float* x      = (const float*)d_in[0];
    const float* angle  = (const float*)d_in[1];
    const float* mol    = (const float*)d_in[2];
    const float* gen    = (const float*)d_in[3];
    const int*   src    = (const int*)d_in[4];
    const int*   dst    = (const int*)d_in[5];
    const float* mask   = (const float*)d_in[6];
    const float* mw1    = (const float*)d_in[7];
    const float* mb1    = (const float*)d_in[8];
    const float* mw2    = (const float*)d_in[9];
    const float* mb2    = (const float*)d_in[10];
    const float* mw3    = (const float*)d_in[11];
    const float* mb3    = (const float*)d_in[12];
    const float* wq     = (const float*)d_in[13];
    const float* bq     = (const float*)d_in[14];
    const float* wk     = (const float*)d_in[15];
    const float* bk     = (const float*)d_in[16];
    const float* wv     = (const float*)d_in[17];
    const float* bv     = (const float*)d_in[18];
    const float* we     = (const float*)d_in[19];
    const float* wskip  = (const float*)d_in[20];
    const float* bskip  = (const float*)d_in[21];
    const float* hw1    = (const float*)d_in[22];
    const float* hb1    = (const float*)d_in[23];
    const float* hw2    = (const float*)d_in[24];
    const float* hb2    = (const float*)d_in[25];
    const float* hw3    = (const float*)d_in[26];
    const float* hb3    = (const float*)d_in[27];
    float* out = (float*)d_out;

    char* p = (char*)d_ws;
    auto alloc = [&](size_t bytes) -> void* {
        void* r = (void*)p;
        p += (bytes + 255) & ~(size_t)255;
        return r;
    };
    int*   row_off = (int*)alloc((NN + 1) * 4);
    float* selff   = (float*)alloc((size_t)NN * 20 * 4);
    __hip_bfloat16* selffb = (__hip_bfloat16*)alloc((size_t)NN * 32 * 2);
    float* qf      = (float*)alloc((size_t)NN * 128 * 4);
    float* qkp     = (float*)alloc((size_t)NN * 64 * 4);
    float* skipf   = (float*)alloc((size_t)NN * 64 * 4);
    float* qwe     = (float*)alloc((size_t)NN * 168 * 4);
    float* outb    = (float*)alloc((size_t)NN * 64 * 4);
    __hip_bfloat16* W1b = (__hip_bfloat16*)alloc(2048 * 2);
    __hip_bfloat16* W2b = (__hip_bfloat16*)alloc(4096 * 2);
    __hip_bfloat16* W3b = (__hip_bfloat16*)alloc(4096 * 2);
    __hip_bfloat16* H1b = (__hip_bfloat16*)alloc(4096 * 2);
    __hip_bfloat16* H2b = (__hip_bfloat16*)alloc(4096 * 2);
    __hip_bfloat16* H3b = (__hip_bfloat16*)alloc(2048 * 2);
    float* weT     = (float*)alloc(10752 * 4);
    __hip_bfloat16* msg = (__hip_bfloat16*)alloc((size_t)EF * 64 * 2);

    k_prep<<<123, 256, 0, stream>>>(mw1, mb1, mw2, mw3, hw1, hw2, hw3, we,
                                    W1b, W2b, W3b, H1b, H2b, H3b, weT);
    k_csr<<<(NN + 256) / 256, 256, 0, stream>>>(dst, mask, row_off);
    k_node<<<NN / 4, 256, 0, stream>>>(angle, mol, gen, row_off, wq, bq, wk, bk,
                                       wskip, bskip, weT, selff, selffb, qf, skipf, qwe, qkp);
    k_edge_mfma<<<(EF / 64 + 3) / 4, 256, 0, stream>>>(x, angle, mol, src, dst,
                                                       W1b, W2b, W3b, mb2, mb3, msg);
    k_attn<<<NN / 4, 256, 0, stream>>>(row_off, src, msg, selffb, qkp,
                                       qwe, selff, skipf, we, wv, bv, outb);
    k_final_mfma<<<(NN + 63) / 64, 64, 0, stream>>>(outb, H1b, H2b, H3b, hb1, hb2, hb3, out);
}

// Round 7
// 203.370 us; speedup vs baseline: 1.0782x; 1.0782x over previous
//
#include <hip/hip_runtime.h>
#include <hip/hip_bf16.h>
#include <math.h>

#define NN 20000
#define EF 720000

typedef float  f4 __attribute__((ext_vector_type(4)));
typedef unsigned int u4 __attribute__((ext_vector_type(4)));

__device__ __forceinline__ void MFMA(f4& c, u4 a, u4 b) {
    asm("v_mfma_f32_16x16x32_bf16 %0, %1, %2, %0" : "+v"(c) : "v"(a), "v"(b));
}

__device__ __forceinline__ unsigned pk(float a, float b) {
    __hip_bfloat162 t = __halves2bfloat162(__float2bfloat16(a), __float2bfloat16(b));
    unsigned u; __builtin_memcpy(&u, &t, 4); return u;
}
__device__ __forceinline__ float bf2f(unsigned short u) {
    return __builtin_bit_cast(float, (unsigned)u << 16);
}
__device__ __forceinline__ f4 bf2f4(ushort4 u) {
    f4 r; r.x = bf2f(u.x); r.y = bf2f(u.y); r.z = bf2f(u.z); r.w = bf2f(u.w); return r;
}
__device__ __forceinline__ float dot4(f4 a, f4 b) {
    return a.x * b.x + a.y * b.y + a.z * b.z + a.w * b.w;
}
__device__ __forceinline__ void fma4(f4& acc, float w, f4 v) {
    acc.x += w * v.x; acc.y += w * v.y; acc.z += w * v.z; acc.w += w * v.w;
}

// ---------------------------------------------------------------- prep: bf16 weights + transposes
__global__ __launch_bounds__(256) void k_prep(
    const float* __restrict__ mw1, const float* __restrict__ mb1,
    const float* __restrict__ mw2, const float* __restrict__ mw3,
    const float* __restrict__ hw1, const float* __restrict__ hw2, const float* __restrict__ hw3,
    const float* __restrict__ we, const float* __restrict__ wk, const float* __restrict__ bk,
    __hip_bfloat16* __restrict__ W1b, __hip_bfloat16* __restrict__ W2b, __hip_bfloat16* __restrict__ W3b,
    __hip_bfloat16* __restrict__ H1b, __hip_bfloat16* __restrict__ H2b, __hip_bfloat16* __restrict__ H3b,
    float* __restrict__ weT, float* __restrict__ wkT)
{
    int t = blockIdx.x * 256 + threadIdx.x;
    if (t < 2048) {  // W1b[ch][k], K=32: k<21 weights, k==21 bias, rest 0
        int ch = t >> 5, k = t & 31;
        float v = (k < 21) ? mw1[k * 64 + ch] : (k == 21 ? mb1[ch] : 0.f);
        W1b[t] = __float2bfloat16(v); return;
    }
    t -= 2048;
    if (t < 4096) { int ch = t >> 6, k = t & 63; W2b[t] = __float2bfloat16(mw2[k * 64 + ch]); return; }
    t -= 4096;
    if (t < 4096) { int ch = t >> 6, k = t & 63; W3b[t] = __float2bfloat16(mw3[k * 64 + ch]); return; }
    t -= 4096;
    if (t < 4096) { int ch = t >> 6, k = t & 63; H1b[t] = __float2bfloat16(hw1[k * 64 + ch]); return; }
    t -= 4096;
    if (t < 4096) { int ch = t >> 6, k = t & 63; H2b[t] = __float2bfloat16(hw2[k * 64 + ch]); return; }
    t -= 4096;
    if (t < 2048) {  // H3b padded to 32 rows
        int ch = t >> 6, k = t & 63;
        float v = (ch < 20) ? hw3[k * 20 + ch] : 0.f;
        H3b[t] = __float2bfloat16(v); return;
    }
    t -= 2048;
    if (t < 10752) { int cf = t / 84, a = t % 84; weT[t] = we[a * 128 + cf]; return; }
    t -= 10752;
    if (t < 4096) {  // wkT[cf][32]: a<20 -> wk row a, a==20 -> bk (bias as extra row), rest 0
        int cf = t >> 5, a = t & 31;
        float v = (a < 20) ? wk[a * 128 + cf] : (a == 20 ? bk[cf] : 0.f);
        wkT[t] = v; return;
    }
}

// ---------------------------------------------------------------- CSR via binary search
__global__ __launch_bounds__(256) void k_csr(
    const int* __restrict__ dst, const float* __restrict__ mask, int* __restrict__ row_off)
{
    int n = blockIdx.x * 256 + threadIdx.x;
    if (n > NN) return;
    int lo = 0, hi = EF;
    while (lo < hi) { int mid = (lo + hi) >> 1; if (mask[mid] > 0.5f) lo = mid + 1; else hi = mid; }
    int Ea = lo;
    lo = 0; hi = Ea;
    while (lo < hi) { int mid = (lo + hi) >> 1; if (dst[mid] < n) lo = mid + 1; else hi = mid; }
    row_off[n] = lo;
}

// ---------------------------------------------------------------- node features + projections
// selffb[n][32] bf16: [0..19]=self_feat, [20]=1.0 (bias slot), rest 0
// qkp[n][64] f32: [h*32+a] = sum_c q_h[c]*wkT[(h*64+c)*32+a]  (a=20 slot = bk_h.q_h, rest 0)
__global__ __launch_bounds__(256) void k_node(
    const float* __restrict__ angle, const float* __restrict__ mol, const float* __restrict__ gen,
    const int* __restrict__ row_off,
    const float* __restrict__ wq, const float* __restrict__ bq,
    const float* __restrict__ wskip, const float* __restrict__ bskip,
    const float* __restrict__ weT, const float* __restrict__ wkT,
    float* __restrict__ selff, __hip_bfloat16* __restrict__ selffb,
    float* __restrict__ skipf, float* __restrict__ qwe, float* __restrict__ qkp)
{
    __shared__ float qlds[4 * 128];
    int wid = threadIdx.x >> 6, lane = threadIdx.x & 63;
    int n = blockIdx.x * 4 + wid;

    float an = angle[n];
    float sv, cv; sincosf(an, &sv, &cv);
    float degf = (float)(row_off[n + 1] - row_off[n]);
    float sf[20];
    sf[0] = sv; sf[1] = cv;
#pragma unroll
    for (int j = 0; j < 16; j++) sf[2 + j] = mol[n * 16 + j];
    sf[18] = gen[n];
    sf[19] = degf;

    float sval = (lane == 0) ? sv : (lane == 1) ? cv :
                 (lane < 18) ? mol[n * 16 + (lane - 2)] :
                 (lane == 18) ? gen[n] : degf;
    if (lane < 20) selff[n * 20 + lane] = sval;
    if (lane < 32) {
        float v = (lane < 20) ? sval : (lane == 20 ? 1.f : 0.f);
        selffb[n * 32 + lane] = __float2bfloat16(v);
    }

    float q0 = bq[lane], q1 = bq[64 + lane];
    float sk = bskip[lane];
#pragma unroll
    for (int a = 0; a < 20; a++) {
        float s = sf[a];
        q0 += s * wq[a * 128 + lane];  q1 += s * wq[a * 128 + 64 + lane];
        sk += s * wskip[a * 64 + lane];
    }
    skipf[n * 64 + lane] = sk;
    qlds[wid * 128 + lane] = q0; qlds[wid * 128 + 64 + lane] = q1;
    __syncthreads();

    // qwe[n][h][a] = sum_c q[h][c] * we[a][h*64+c]   (weT coalesced over a)
#pragma unroll
    for (int r = 0; r < 3; r++) {
        int o = r * 64 + lane;
        if (o < 168) {
            int h = (o >= 84) ? 1 : 0;
            int a = o - 84 * h;
            float acc = 0.f, acc2 = 0.f;
#pragma unroll
            for (int c = 0; c < 64; c += 2) {
                acc  += qlds[wid * 128 + h * 64 + c]     * weT[(h * 64 + c) * 84 + a];
                acc2 += qlds[wid * 128 + h * 64 + c + 1] * weT[(h * 64 + c + 1) * 84 + a];
            }
            qwe[n * 168 + o] = acc + acc2;
        }
    }

    // qk projection via transposed table (coalesced over a; bias folded as row 20)
    {
        int h = lane >> 5, a = lane & 31;
        float acc = 0.f, acc2 = 0.f;
#pragma unroll
        for (int c = 0; c < 64; c += 2) {
            acc  += qlds[wid * 128 + h * 64 + c]     * wkT[(h * 64 + c) * 32 + a];
            acc2 += qlds[wid * 128 + h * 64 + c + 1] * wkT[(h * 64 + c + 1) * 32 + a];
        }
        qkp[n * 64 + lane] = acc + acc2;
    }
}

// ---------------------------------------------------------------- edge MLP via MFMA (wave = 64 edges, 4 waves/block)
__device__ __forceinline__ void write_tiles(char* lds, int l, f4 (&acc)[4][4], const float* bias)
{
#pragma unroll
    for (int m = 0; m < 4; m++) {
        f4 bv;
        if (bias) bv = *(const f4*)(bias + m * 16 + ((l >> 4) << 2));
        else      { bv.x = 0.f; bv.y = 0.f; bv.z = 0.f; bv.w = 0.f; }
#pragma unroll
        for (int n = 0; n < 4; n++) {
            f4 v = acc[m][n];
            float v0 = fmaxf(v.x + bv.x, 0.f);
            float v1 = fmaxf(v.y + bv.y, 0.f);
            float v2 = fmaxf(v.z + bv.z, 0.f);
            float v3 = fmaxf(v.w + bv.w, 0.f);
            int e   = n * 16 + (l & 15);
            int ch0 = m * 16 + ((l >> 4) << 2);
            int byte = e * 128 + ((((ch0 >> 3) ^ (e & 7))) << 4) + (ch0 & 7) * 2;
            uint2 w; w.x = pk(v0, v1); w.y = pk(v2, v3);
            *(uint2*)(lds + byte) = w;
        }
    }
}

__global__ __launch_bounds__(256) void k_edge_mfma(
    const float* __restrict__ x, const float* __restrict__ angle, const float* __restrict__ mol,
    const int* __restrict__ src, const int* __restrict__ dst,
    const __hip_bfloat16* __restrict__ W1b, const __hip_bfloat16* __restrict__ W2b,
    const __hip_bfloat16* __restrict__ W3b,
    const float* __restrict__ mb2, const float* __restrict__ mb3,
    __hip_bfloat16* __restrict__ msg)
{
    __shared__ char lds_all[4][64 * 128];
    int wv = threadIdx.x >> 6, l = threadIdx.x & 63;
    char* lds = lds_all[wv];
    int e0 = (blockIdx.x * 4 + wv) * 64;
    if (e0 + 64 > EF) e0 = EF - 64;

    int s = src[e0 + l], d = dst[e0 + l];
    float2 xs = ((const float2*)x)[s], xd = ((const float2*)x)[d];
    float dx = xs.x - xd.x, dy = xs.y - xd.y;
    float r = sqrtf(fmaxf(dx * dx + dy * dy, 1e-12f));
    float da = angle[s] - angle[d];
    float sv, cv; sincosf(da, &sv, &cv);
    const float4* m4 = (const float4*)mol;
    float4 sa = m4[s * 4 + 0], sb = m4[s * 4 + 1], sc = m4[s * 4 + 2], sd = m4[s * 4 + 3];
    float4 ta = m4[d * 4 + 0], tb = m4[d * 4 + 1], tc = m4[d * 4 + 2], td = m4[d * 4 + 3];
    float f[22];
    f[0] = dx; f[1] = dy; f[2] = r; f[3] = sv; f[4] = cv;
    f[5]  = sa.x - ta.x; f[6]  = sa.y - ta.y; f[7]  = sa.z - ta.z; f[8]  = sa.w - ta.w;
    f[9]  = sb.x - tb.x; f[10] = sb.y - tb.y; f[11] = sb.z - tb.z; f[12] = sb.w - tb.w;
    f[13] = sc.x - tc.x; f[14] = sc.y - tc.y; f[15] = sc.z - tc.z; f[16] = sc.w - tc.w;
    f[17] = sd.x - td.x; f[18] = sd.y - td.y; f[19] = sd.z - td.z; f[20] = sd.w - td.w;
    f[21] = 1.f;
    unsigned p[16];
#pragma unroll
    for (int j = 0; j < 11; j++) p[j] = pk(f[2 * j], f[2 * j + 1]);
#pragma unroll
    for (int j = 11; j < 16; j++) p[j] = 0u;
#pragma unroll
    for (int g = 0; g < 4; g++) {
        int byte = l * 64 + ((g ^ (l & 3)) << 4);
        u4 w; w.x = p[4 * g]; w.y = p[4 * g + 1]; w.z = p[4 * g + 2]; w.w = p[4 * g + 3];
        *(u4*)(lds + byte) = w;
    }
    __syncthreads();

    u4 B1[4];
#pragma unroll
    for (int n = 0; n < 4; n++) {
        int e = n * 16 + (l & 15);
        int byte = e * 64 + ((((l >> 4) & 3) ^ (e & 3)) << 4);
        B1[n] = *(const u4*)(lds + byte);
    }
    __syncthreads();

    f4 acc[4][4];
#pragma unroll
    for (int m = 0; m < 4; m++)
#pragma unroll
        for (int n = 0; n < 4; n++) { acc[m][n].x = 0.f; acc[m][n].y = 0.f; acc[m][n].z = 0.f; acc[m][n].w = 0.f; }

    const unsigned short* W1u = (const unsigned short*)W1b;
    const unsigned short* W2u = (const unsigned short*)W2b;
    const unsigned short* W3u = (const unsigned short*)W3b;
#pragma unroll
    for (int m = 0; m < 4; m++) {
        u4 w = *(const u4*)(W1u + (m * 16 + (l & 15)) * 32 + (l >> 4) * 8);
#pragma unroll
        for (int n = 0; n < 4; n++) MFMA(acc[m][n], w, B1[n]);
    }
    write_tiles(lds, l, acc, nullptr);
    __syncthreads();

    u4 B2[4][2];
#pragma unroll
    for (int n = 0; n < 4; n++)
#pragma unroll
        for (int ks = 0; ks < 2; ks++) {
            int e = n * 16 + (l & 15);
            int g = ks * 4 + (l >> 4);
            B2[n][ks] = *(const u4*)(lds + e * 128 + ((g ^ (e & 7)) << 4));
        }
    __syncthreads();
#pragma unroll
    for (int m = 0; m < 4; m++)
#pragma unroll
        for (int n = 0; n < 4; n++) { acc[m][n].x = 0.f; acc[m][n].y = 0.f; acc[m][n].z = 0.f; acc[m][n].w = 0.f; }
#pragma unroll
    for (int m = 0; m < 4; m++)
#pragma unroll
        for (int ks = 0; ks < 2; ks++) {
            u4 w = *(const u4*)(W2u + (m * 16 + (l & 15)) * 64 + ks * 32 + (l >> 4) * 8);
#pragma unroll
            for (int n = 0; n < 4; n++) MFMA(acc[m][n], w, B2[n][ks]);
        }
    write_tiles(lds, l, acc, mb2);
    __syncthreads();

#pragma unroll
    for (int n = 0; n < 4; n++)
#pragma unroll
        for (int ks = 0; ks < 2; ks++) {
            int e = n * 16 + (l & 15);
            int g = ks * 4 + (l >> 4);
            B2[n][ks] = *(const u4*)(lds + e * 128 + ((g ^ (e & 7)) << 4));
        }
    __syncthreads();
#pragma unroll
    for (int m = 0; m < 4; m++)
#pragma unroll
        for (int n = 0; n < 4; n++) { acc[m][n].x = 0.f; acc[m][n].y = 0.f; acc[m][n].z = 0.f; acc[m][n].w = 0.f; }
#pragma unroll
    for (int m = 0; m < 4; m++)
#pragma unroll
        for (int ks = 0; ks < 2; ks++) {
            u4 w = *(const u4*)(W3u + (m * 16 + (l & 15)) * 64 + ks * 32 + (l >> 4) * 8);
#pragma unroll
            for (int n = 0; n < 4; n++) MFMA(acc[m][n], w, B2[n][ks]);
        }
    write_tiles(lds, l, acc, mb3);
    __syncthreads();

#pragma unroll
    for (int it = 0; it < 8; it++) {
        int e = it * 8 + (l >> 3);
        int g = l & 7;
        u4 vv = *(const u4*)(lds + e * 128 + ((g ^ (e & 7)) << 4));
        *(u4*)((unsigned short*)msg + (size_t)(e0 + e) * 64 + g * 8) = vv;
    }
}

// ---------------------------------------------------------------- attention aggregate
// wave = node; 4 edge-groups of 16 lanes. Per edge gather: msg (128B) + selffb (64B).
__global__ __launch_bounds__(256) void k_attn(
    const int* __restrict__ row_off, const int* __restrict__ src,
    const __hip_bfloat16* __restrict__ msg,
    const __hip_bfloat16* __restrict__ selffb, const float* __restrict__ qkp,
    const float* __restrict__ qwe, const float* __restrict__ selff, const float* __restrict__ skipf,
    const float* __restrict__ we, const float* __restrict__ wv, const float* __restrict__ bv,
    float* __restrict__ outb)
{
    __shared__ float redm[4][2][64];
    __shared__ float reds[4][2][32];
    int tid = threadIdx.x, wid = tid >> 6, lane = tid & 63;
    int g = lane >> 4, c16 = lane & 15;
    int n = blockIdx.x * 4 + wid;

    f4 qm0 = *(const f4*)(qwe + n * 168 + 4 * c16);
    f4 qm1 = *(const f4*)(qwe + n * 168 + 84 + 4 * c16);
    float2 qk0 = *(const float2*)(qkp + n * 64 + 2 * c16);
    float2 qk1 = *(const float2*)(qkp + n * 64 + 32 + 2 * c16);

    float a00 = 0.f, a01 = 0.f;
#pragma unroll
    for (int j = 0; j < 20; j++) {
        float sfj = selff[n * 20 + j];
        a00 += sfj * qwe[n * 168 + 64 + j];
        a01 += sfj * qwe[n * 168 + 84 + 64 + j];
    }

    const unsigned short* msgu = (const unsigned short*)msg;
    const unsigned short* sfu  = (const unsigned short*)selffb;
    int r0 = row_off[n], r1 = row_off[n + 1];
    int nit = (r1 - r0 + 3) >> 2;

    f4 Wm0 = {0,0,0,0}, Wm1 = {0,0,0,0};
    float Ws00 = 0.f, Ws01 = 0.f, Ws10 = 0.f, Ws11 = 0.f;
    float S0 = 0.f, S1 = 0.f;

#pragma unroll 2
    for (int it = 0; it < nit; it++) {
        int e = r0 + it * 4 + g;
        bool ok = (e < r1);
        int ec = ok ? e : r0;
        int s = src[ec];
        ushort2 su = *(const ushort2*)(sfu + (size_t)s * 32 + 2 * c16);
        float sf0 = bf2f(su.x), sf1 = bf2f(su.y);
        f4 mc = bf2f4(*(const ushort4*)(msgu + (size_t)ec * 64 + 4 * c16));

        float t0 = dot4(qm0, mc) + sf0 * qk0.x + sf1 * qk0.y;
        float t1 = dot4(qm1, mc) + sf0 * qk1.x + sf1 * qk1.y;
#pragma unroll
        for (int mk = 1; mk < 16; mk <<= 1) {
            t0 += __shfl_xor(t0, mk, 64);
            t1 += __shfl_xor(t1, mk, 64);
        }
        float w0 = ok ? __expf((t0 + a00) * 0.125f) : 0.f;
        float w1 = ok ? __expf((t1 + a01) * 0.125f) : 0.f;
        S0 += w0; S1 += w1;
        fma4(Wm0, w0, mc); fma4(Wm1, w1, mc);
        Ws00 += w0 * sf0; Ws01 += w0 * sf1;
        Ws10 += w1 * sf0; Ws11 += w1 * sf1;
    }

    // cross-group reduce
#pragma unroll
    for (int mk = 16; mk <= 32; mk <<= 1) {
        Wm0.x += __shfl_xor(Wm0.x, mk, 64); Wm0.y += __shfl_xor(Wm0.y, mk, 64);
        Wm0.z += __shfl_xor(Wm0.z, mk, 64); Wm0.w += __shfl_xor(Wm0.w, mk, 64);
        Wm1.x += __shfl_xor(Wm1.x, mk, 64); Wm1.y += __shfl_xor(Wm1.y, mk, 64);
        Wm1.z += __shfl_xor(Wm1.z, mk, 64); Wm1.w += __shfl_xor(Wm1.w, mk, 64);
        Ws00 += __shfl_xor(Ws00, mk, 64); Ws01 += __shfl_xor(Ws01, mk, 64);
        Ws10 += __shfl_xor(Ws10, mk, 64); Ws11 += __shfl_xor(Ws11, mk, 64);
        S0 += __shfl_xor(S0, mk, 64); S1 += __shfl_xor(S1, mk, 64);
    }

    if (g == 0) {
        *(f4*)(&redm[wid][0][4 * c16]) = Wm0;
        *(f4*)(&redm[wid][1][4 * c16]) = Wm1;
        float2 s0; s0.x = Ws00; s0.y = Ws01;
        float2 s1; s1.x = Ws10; s1.y = Ws11;
        *(float2*)(&reds[wid][0][2 * c16]) = s0;
        *(float2*)(&reds[wid][1][2 * c16]) = s1;
    }
    // same-wave LDS write->read; lgkmcnt ordering handled by compiler (validated r2-r6).

    const float* wmA = &redm[wid][0][0];
    const float* wmB = &redm[wid][1][0];
    const float* wsA = &reds[wid][0][0];
    const float* wsB = &reds[wid][1][0];
    float acc0 = S0 * bv[lane], acc1 = S1 * bv[64 + lane];
#pragma unroll 4
    for (int a = 0; a < 64; a += 2) {
        acc0 += wmA[a] * we[a * 128 + lane]      + wmA[a + 1] * we[(a + 1) * 128 + lane];
        acc1 += wmB[a] * we[a * 128 + 64 + lane] + wmB[a + 1] * we[(a + 1) * 128 + 64 + lane];
    }
#pragma unroll
    for (int j = 0; j < 20; j++) {
        float sfj = selff[n * 20 + j];
        acc0 += S0 * sfj * we[(64 + j) * 128 + lane];
        acc1 += S1 * sfj * we[(64 + j) * 128 + 64 + lane];
    }
#pragma unroll 2
    for (int a = 0; a < 20; a += 2) {
        acc0 += wsA[a] * wv[a * 128 + lane]      + wsA[a + 1] * wv[(a + 1) * 128 + lane];
        acc1 += wsB[a] * wv[a * 128 + 64 + lane] + wsB[a + 1] * wv[(a + 1) * 128 + 64 + lane];
    }
    float o0 = acc0 / (S0 + 1e-16f);
    float o1 = acc1 / (S1 + 1e-16f);
    outb[n * 64 + lane] = 0.5f * (o0 + o1) + skipf[n * 64 + lane];
}

// ---------------------------------------------------------------- final MLP via MFMA (1 wave = 64 nodes)
__global__ __launch_bounds__(64) void k_final_mfma(
    const float* __restrict__ outb,
    const __hip_bfloat16* __restrict__ H1b, const __hip_bfloat16* __restrict__ H2b,
    const __hip_bfloat16* __restrict__ H3b,
    const float* __restrict__ hb1, const float* __restrict__ hb2, const float* __restrict__ hb3,
    float* __restrict__ out)
{
    __shared__ char lds[64 * 128];
    int l = threadIdx.x;
    int n0 = blockIdx.x * 64;
    int nl = n0 + l;
    int nn = (nl < NN) ? nl : (NN - 1);

    const float* row = outb + (size_t)nn * 64;
#pragma unroll
    for (int g = 0; g < 8; g++) {
        u4 w;
        w.x = pk(row[8 * g + 0], row[8 * g + 1]);
        w.y = pk(row[8 * g + 2], row[8 * g + 3]);
        w.z = pk(row[8 * g + 4], row[8 * g + 5]);
        w.w = pk(row[8 * g + 6], row[8 * g + 7]);
        *(u4*)(lds + l * 128 + ((g ^ (l & 7)) << 4)) = w;
    }
    __syncthreads();

    const unsigned short* H1u = (const unsigned short*)H1b;
    const unsigned short* H2u = (const unsigned short*)H2b;
    const unsigned short* H3u = (const unsigned short*)H3b;

    u4 B[4][2];
    f4 acc[4][4];

    // ---- stage 1
#pragma unroll
    for (int n = 0; n < 4; n++)
#pragma unroll
        for (int ks = 0; ks < 2; ks++) {
            int e = n * 16 + (l & 15);
            int g = ks * 4 + (l >> 4);
            B[n][ks] = *(const u4*)(lds + e * 128 + ((g ^ (e & 7)) << 4));
        }
    __syncthreads();
#pragma unroll
    for (int m = 0; m < 4; m++)
#pragma unroll
        for (int n = 0; n < 4; n++) { acc[m][n].x = 0.f; acc[m][n].y = 0.f; acc[m][n].z = 0.f; acc[m][n].w = 0.f; }
#pragma unroll
    for (int m = 0; m < 4; m++)
#pragma unroll
        for (int ks = 0; ks < 2; ks++) {
            u4 w = *(const u4*)(H1u + (m * 16 + (l & 15)) * 64 + ks * 32 + (l >> 4) * 8);
#pragma unroll
            for (int n = 0; n < 4; n++) MFMA(acc[m][n], w, B[n][ks]);
        }
    write_tiles(lds, l, acc, hb1);
    __syncthreads();

    // ---- stage 2
#pragma unroll
    for (int n = 0; n < 4; n++)
#pragma unroll
        for (int ks = 0; ks < 2; ks++) {
            int e = n * 16 + (l & 15);
            int g = ks * 4 + (l >> 4);
            B[n][ks] = *(const u4*)(lds + e * 128 + ((g ^ (e & 7)) << 4));
        }
    __syncthreads();
#pragma unroll
    for (int m = 0; m < 4; m++)
#pragma unroll
        for (int n = 0; n < 4; n++) { acc[m][n].x = 0.f; acc[m][n].y = 0.f; acc[m][n].z = 0.f; acc[m][n].w = 0.f; }
#pragma unroll
    for (int m = 0; m < 4; m++)
#pragma unroll
        for (int ks = 0; ks < 2; ks++) {
            u4 w = *(const u4*)(H2u + (m * 16 + (l & 15)) * 64 + ks * 32 + (l >> 4) * 8);
#pragma unroll
            for (int n = 0; n < 4; n++) MFMA(acc[m][n], w, B[n][ks]);
        }
    write_tiles(lds, l, acc, hb2);
    __syncthreads();

    // ---- stage 3: 64 -> 20
#pragma unroll
    for (int n = 0; n < 4; n++)
#pragma unroll
        for (int ks = 0; ks < 2; ks++) {
            int e = n * 16 + (l & 15);
            int g = ks * 4 + (l >> 4);
            B[n][ks] = *(const u4*)(lds + e * 128 + ((g ^ (e & 7)) << 4));
        }

    f4 acc3[2][4];
#pragma unroll
    for (int m = 0; m < 2; m++)
#pragma unroll
        for (int n = 0; n < 4; n++) { acc3[m][n].x = 0.f; acc3[m][n].y = 0.f; acc3[m][n].z = 0.f; acc3[m][n].w = 0.f; }
#pragma unroll
    for (int m = 0; m < 2; m++)
#pragma unroll
        for (int ks = 0; ks < 2; ks++) {
            u4 w = *(const u4*)(H3u + (m * 16 + (l & 15)) * 64 + ks * 32 + (l >> 4) * 8);
#pragma unroll
            for (int n = 0; n < 4; n++) MFMA(acc3[m][n], w, B[n][ks]);
        }

#pragma unroll
    for (int m = 0; m < 2; m++) {
#pragma unroll
        for (int j = 0; j < 4; j++) {
            int ch = m * 16 + (l >> 4) * 4 + j;
            if (ch < 20) {
                float b = hb3[ch];
#pragma unroll
                for (int nt = 0; nt < 4; nt++) {
                    int node = n0 + nt * 16 + (l & 15);
                    if (node < NN) {
                        float v = acc3[m][nt][j] + b;
                        if (ch < 2)       out[node * 2 + ch] = v;
                        else if (ch == 2) out[2 * NN + node] = v;
                        else if (ch < 19) out[3 * NN + node * 16 + (ch - 3)] = v;
                        else              out[19 * NN + node] = v;
                    }
                }
            }
        }
    }
}

// ---------------------------------------------------------------- launch
extern "C" void kernel_launch(void* const* d_in, const int* in_sizes, int n_in,
                              void* d_out, int out_size, void* d_ws, size_t ws_size,
                              hipStream_t stream)
{
    const float* x      = (const float*)d_in[0];
    const float* angle  = (const float*)d_in[1];
    const float* mol    = (const float*)d_in[2];
    const float* gen    = (const float*)d_in[3];
    const int*   src    = (const int*)d_in[4];
    const int*   dst    = (const int*)d_in[5];
    const float* mask   = (const float*)d_in[6];
    const float* mw1    = (const float*)d_in[7];
    const float* mb1    = (const float*)d_in[8];
    const float* mw2    = (const float*)d_in[9];
    const float* mb2    = (const float*)d_in[10];
    const float* mw3    = (const float*)d_in[11];
    const float* mb3    = (const float*)d_in[12];
    const float* wq     = (const float*)d_in[13];
    const float* bq     = (const float*)d_in[14];
    const float* wk     = (const float*)d_in[15];
    const float* bk     = (const float*)d_in[16];
    const float* wv     = (const float*)d_in[17];
    const float* bv     = (const float*)d_in[18];
    const float* we     = (const float*)d_in[19];
    const float* wskip  = (const float*)d_in[20];
    const float* bskip  = (const float*)d_in[21];
    const float* hw1    = (const float*)d_in[22];
    const float* hb1    = (const float*)d_in[23];
    const float* hw2    = (const float*)d_in[24];
    const float* hb2    = (const float*)d_in[25];
    const float* hw3    = (const float*)d_in[26];
    const float* hb3    = (const float*)d_in[27];
    float* out = (float*)d_out;

    char* p = (char*)d_ws;
    auto alloc = [&](size_t bytes) -> void* {
        void* r = (void*)p;
        p += (bytes + 255) & ~(size_t)255;
        return r;
    };
    int*   row_off = (int*)alloc((NN + 1) * 4);
    float* selff   = (float*)alloc((size_t)NN * 20 * 4);
    __hip_bfloat16* selffb = (__hip_bfloat16*)alloc((size_t)NN * 32 * 2);
    float* qkp     = (float*)alloc((size_t)NN * 64 * 4);
    float* skipf   = (float*)alloc((size_t)NN * 64 * 4);
    float* qwe     = (float*)alloc((size_t)NN * 168 * 4);
    float* outb    = (float*)alloc((size_t)NN * 64 * 4);
    __hip_bfloat16* W1b = (__hip_bfloat16*)alloc(2048 * 2);
    __hip_bfloat16* W2b = (__hip_bfloat16*)alloc(4096 * 2);
    __hip_bfloat16* W3b = (__hip_bfloat16*)alloc(4096 * 2);
    __hip_bfloat16* H1b = (__hip_bfloat16*)alloc(4096 * 2);
    __hip_bfloat16* H2b = (__hip_bfloat16*)alloc(4096 * 2);
    __hip_bfloat16* H3b = (__hip_bfloat16*)alloc(2048 * 2);
    float* weT     = (float*)alloc(10752 * 4);
    float* wkT     = (float*)alloc(4096 * 4);
    __hip_bfloat16* msg = (__hip_bfloat16*)alloc((size_t)EF * 64 * 2);

    k_prep<<<138, 256, 0, stream>>>(mw1, mb1, mw2, mw3, hw1, hw2, hw3, we, wk, bk,
                                    W1b, W2b, W3b, H1b, H2b, H3b, weT, wkT);
    k_csr<<<(NN + 256) / 256, 256, 0, stream>>>(dst, mask, row_off);
    k_node<<<NN / 4, 256, 0, stream>>>(angle, mol, gen, row_off, wq, bq,
                                       wskip, bskip, weT, wkT,
                                       selff, selffb, skipf, qwe, qkp);
    k_edge_mfma<<<(EF / 64 + 3) / 4, 256, 0, stream>>>(x, angle, mol, src, dst,
                                                       W1b, W2b, W3b, mb2, mb3, msg);
    k_attn<<<NN / 4, 256, 0, stream>>>(row_off, src, msg, selffb, qkp,
                                       qwe, selff, skipf, we, wv, bv, outb);
    k_final_mfma<<<(NN + 63) / 64, 64, 0, stream>>>(outb, H1b, H2b, H3b, hb1, hb2, hb3, out);
}

// Round 9
// 183.911 us; speedup vs baseline: 1.1923x; 1.1058x over previous
//
#include <hip/hip_runtime.h>
#include <hip/hip_bf16.h>
#include <math.h>

#define NN 20000
#define EF 720000

typedef float  f4 __attribute__((ext_vector_type(4)));
typedef unsigned int u4 __attribute__((ext_vector_type(4)));

__device__ __forceinline__ void MFMA(f4& c, u4 a, u4 b) {
    asm("v_mfma_f32_16x16x32_bf16 %0, %1, %2, %0" : "+v"(c) : "v"(a), "v"(b));
}

__device__ __forceinline__ unsigned pk(float a, float b) {
    __hip_bfloat162 t = __halves2bfloat162(__float2bfloat16(a), __float2bfloat16(b));
    unsigned u; __builtin_memcpy(&u, &t, 4); return u;
}
__device__ __forceinline__ float bf2f(unsigned short u) {
    return __builtin_bit_cast(float, (unsigned)u << 16);
}
__device__ __forceinline__ f4 bf2f4(ushort4 u) {
    f4 r; r.x = bf2f(u.x); r.y = bf2f(u.y); r.z = bf2f(u.z); r.w = bf2f(u.w); return r;
}
__device__ __forceinline__ float dot4(f4 a, f4 b) {
    return a.x * b.x + a.y * b.y + a.z * b.z + a.w * b.w;
}
__device__ __forceinline__ void fma4(f4& acc, float w, f4 v) {
    acc.x += w * v.x; acc.y += w * v.y; acc.z += w * v.z; acc.w += w * v.w;
}

// ---------------------------------------------------------------- prep: bf16 weights + transposes
// WcA[h][ch][k], K=128: k<64 -> we[k][h*64+ch]; 64..83 -> wv[k-64]; 84 -> bv; 85..95 -> 0;
//                       96..115 -> we[64+(k-96)]; 116..127 -> 0
__global__ __launch_bounds__(256) void k_prep(
    const float* __restrict__ mw1, const float* __restrict__ mb1,
    const float* __restrict__ mw2, const float* __restrict__ mw3,
    const float* __restrict__ hw1, const float* __restrict__ hw2, const float* __restrict__ hw3,
    const float* __restrict__ we, const float* __restrict__ wk, const float* __restrict__ bk,
    const float* __restrict__ wv, const float* __restrict__ bv,
    __hip_bfloat16* __restrict__ W1b, __hip_bfloat16* __restrict__ W2b, __hip_bfloat16* __restrict__ W3b,
    __hip_bfloat16* __restrict__ H1b, __hip_bfloat16* __restrict__ H2b, __hip_bfloat16* __restrict__ H3b,
    float* __restrict__ weT, float* __restrict__ wkT, __hip_bfloat16* __restrict__ WcA)
{
    int t = blockIdx.x * 256 + threadIdx.x;
    if (t < 2048) {  // W1b[ch][k], K=32: k<21 weights, k==21 bias, rest 0
        int ch = t >> 5, k = t & 31;
        float v = (k < 21) ? mw1[k * 64 + ch] : (k == 21 ? mb1[ch] : 0.f);
        W1b[t] = __float2bfloat16(v); return;
    }
    t -= 2048;
    if (t < 4096) { int ch = t >> 6, k = t & 63; W2b[t] = __float2bfloat16(mw2[k * 64 + ch]); return; }
    t -= 4096;
    if (t < 4096) { int ch = t >> 6, k = t & 63; W3b[t] = __float2bfloat16(mw3[k * 64 + ch]); return; }
    t -= 4096;
    if (t < 4096) { int ch = t >> 6, k = t & 63; H1b[t] = __float2bfloat16(hw1[k * 64 + ch]); return; }
    t -= 4096;
    if (t < 4096) { int ch = t >> 6, k = t & 63; H2b[t] = __float2bfloat16(hw2[k * 64 + ch]); return; }
    t -= 4096;
    if (t < 2048) {  // H3b padded to 32 rows
        int ch = t >> 6, k = t & 63;
        float v = (ch < 20) ? hw3[k * 20 + ch] : 0.f;
        H3b[t] = __float2bfloat16(v); return;
    }
    t -= 2048;
    if (t < 10752) { int cf = t / 84, a = t % 84; weT[t] = we[a * 128 + cf]; return; }
    t -= 10752;
    if (t < 4096) {  // wkT[cf][32]: a<20 -> wk row a, a==20 -> bk, rest 0
        int cf = t >> 5, a = t & 31;
        float v = (a < 20) ? wk[a * 128 + cf] : (a == 20 ? bk[cf] : 0.f);
        wkT[t] = v; return;
    }
    t -= 4096;
    if (t < 16384) {
        int h = t >> 13, rem = t & 8191;
        int ch = rem >> 7, k = rem & 127;
        int col = h * 64 + ch;
        float v;
        if (k < 64)        v = we[k * 128 + col];
        else if (k < 84)   v = wv[(k - 64) * 128 + col];
        else if (k == 84)  v = bv[col];
        else if (k < 96)   v = 0.f;
        else if (k < 116)  v = we[(64 + (k - 96)) * 128 + col];
        else               v = 0.f;
        WcA[t] = __float2bfloat16(v); return;
    }
}

// ---------------------------------------------------------------- CSR via binary search
__global__ __launch_bounds__(256) void k_csr(
    const int* __restrict__ dst, const float* __restrict__ mask, int* __restrict__ row_off)
{
    int n = blockIdx.x * 256 + threadIdx.x;
    if (n > NN) return;
    int lo = 0, hi = EF;
    while (lo < hi) { int mid = (lo + hi) >> 1; if (mask[mid] > 0.5f) lo = mid + 1; else hi = mid; }
    int Ea = lo;
    lo = 0; hi = Ea;
    while (lo < hi) { int mid = (lo + hi) >> 1; if (dst[mid] < n) lo = mid + 1; else hi = mid; }
    row_off[n] = lo;
}

// ---------------------------------------------------------------- node features + projections
__global__ __launch_bounds__(256) void k_node(
    const float* __restrict__ angle, const float* __restrict__ mol, const float* __restrict__ gen,
    const int* __restrict__ row_off,
    const float* __restrict__ wq, const float* __restrict__ bq,
    const float* __restrict__ wskip, const float* __restrict__ bskip,
    const float* __restrict__ weT, const float* __restrict__ wkT,
    float* __restrict__ selff, __hip_bfloat16* __restrict__ selffb,
    float* __restrict__ skipf, float* __restrict__ qwe, float* __restrict__ qkp)
{
    __shared__ float qlds[4 * 128];
    int wid = threadIdx.x >> 6, lane = threadIdx.x & 63;
    int n = blockIdx.x * 4 + wid;

    float an = angle[n];
    float sv, cv; sincosf(an, &sv, &cv);
    float degf = (float)(row_off[n + 1] - row_off[n]);
    float sf[20];
    sf[0] = sv; sf[1] = cv;
#pragma unroll
    for (int j = 0; j < 16; j++) sf[2 + j] = mol[n * 16 + j];
    sf[18] = gen[n];
    sf[19] = degf;

    float sval = (lane == 0) ? sv : (lane == 1) ? cv :
                 (lane < 18) ? mol[n * 16 + (lane - 2)] :
                 (lane == 18) ? gen[n] : degf;
    if (lane < 20) selff[n * 20 + lane] = sval;
    if (lane < 32) {
        float v = (lane < 20) ? sval : (lane == 20 ? 1.f : 0.f);
        selffb[n * 32 + lane] = __float2bfloat16(v);
    }

    float q0 = bq[lane], q1 = bq[64 + lane];
    float sk = bskip[lane];
#pragma unroll
    for (int a = 0; a < 20; a++) {
        float s = sf[a];
        q0 += s * wq[a * 128 + lane];  q1 += s * wq[a * 128 + 64 + lane];
        sk += s * wskip[a * 64 + lane];
    }
    skipf[n * 64 + lane] = sk;
    qlds[wid * 128 + lane] = q0; qlds[wid * 128 + 64 + lane] = q1;
    __syncthreads();

#pragma unroll
    for (int r = 0; r < 3; r++) {
        int o = r * 64 + lane;
        if (o < 168) {
            int h = (o >= 84) ? 1 : 0;
            int a = o - 84 * h;
            float acc = 0.f, acc2 = 0.f;
#pragma unroll
            for (int c = 0; c < 64; c += 2) {
                acc  += qlds[wid * 128 + h * 64 + c]     * weT[(h * 64 + c) * 84 + a];
                acc2 += qlds[wid * 128 + h * 64 + c + 1] * weT[(h * 64 + c + 1) * 84 + a];
            }
            qwe[n * 168 + o] = acc + acc2;
        }
    }

    {
        int h = lane >> 5, a = lane & 31;
        float acc = 0.f, acc2 = 0.f;
#pragma unroll
        for (int c = 0; c < 64; c += 2) {
            acc  += qlds[wid * 128 + h * 64 + c]     * wkT[(h * 64 + c) * 32 + a];
            acc2 += qlds[wid * 128 + h * 64 + c + 1] * wkT[(h * 64 + c + 1) * 32 + a];
        }
        qkp[n * 64 + lane] = acc + acc2;
    }
}

// ---------------------------------------------------------------- edge MLP via MFMA (wave = 64 edges, 4 waves/block)
__device__ __forceinline__ void write_tiles(char* lds, int l, f4 (&acc)[4][4], const float* bias)
{
#pragma unroll
    for (int m = 0; m < 4; m++) {
        f4 bv;
        if (bias) bv = *(const f4*)(bias + m * 16 + ((l >> 4) << 2));
        else      { bv.x = 0.f; bv.y = 0.f; bv.z = 0.f; bv.w = 0.f; }
#pragma unroll
        for (int n = 0; n < 4; n++) {
            f4 v = acc[m][n];
            float v0 = fmaxf(v.x + bv.x, 0.f);
            float v1 = fmaxf(v.y + bv.y, 0.f);
            float v2 = fmaxf(v.z + bv.z, 0.f);
            float v3 = fmaxf(v.w + bv.w, 0.f);
            int e   = n * 16 + (l & 15);
            int ch0 = m * 16 + ((l >> 4) << 2);
            int byte = e * 128 + ((((ch0 >> 3) ^ (e & 7))) << 4) + (ch0 & 7) * 2;
            uint2 w; w.x = pk(v0, v1); w.y = pk(v2, v3);
            *(uint2*)(lds + byte) = w;
        }
    }
}

__global__ __launch_bounds__(256) void k_edge_mfma(
    const float* __restrict__ x, const float* __restrict__ angle, const float* __restrict__ mol,
    const int* __restrict__ src, const int* __restrict__ dst,
    const __hip_bfloat16* __restrict__ W1b, const __hip_bfloat16* __restrict__ W2b,
    const __hip_bfloat16* __restrict__ W3b,
    const float* __restrict__ mb2, const float* __restrict__ mb3,
    __hip_bfloat16* __restrict__ msg)
{
    __shared__ char lds_all[4][64 * 128];
    int wv = threadIdx.x >> 6, l = threadIdx.x & 63;
    char* lds = lds_all[wv];
    int e0 = (blockIdx.x * 4 + wv) * 64;
    if (e0 + 64 > EF) e0 = EF - 64;

    int s = src[e0 + l], d = dst[e0 + l];
    float2 xs = ((const float2*)x)[s], xd = ((const float2*)x)[d];
    float dx = xs.x - xd.x, dy = xs.y - xd.y;
    float r = sqrtf(fmaxf(dx * dx + dy * dy, 1e-12f));
    float da = angle[s] - angle[d];
    float sv, cv; sincosf(da, &sv, &cv);
    const float4* m4 = (const float4*)mol;
    float4 sa = m4[s * 4 + 0], sb = m4[s * 4 + 1], sc = m4[s * 4 + 2], sd = m4[s * 4 + 3];
    float4 ta = m4[d * 4 + 0], tb = m4[d * 4 + 1], tc = m4[d * 4 + 2], td = m4[d * 4 + 3];
    float f[22];
    f[0] = dx; f[1] = dy; f[2] = r; f[3] = sv; f[4] = cv;
    f[5]  = sa.x - ta.x; f[6]  = sa.y - ta.y; f[7]  = sa.z - ta.z; f[8]  = sa.w - ta.w;
    f[9]  = sb.x - tb.x; f[10] = sb.y - tb.y; f[11] = sb.z - tb.z; f[12] = sb.w - tb.w;
    f[13] = sc.x - tc.x; f[14] = sc.y - tc.y; f[15] = sc.z - tc.z; f[16] = sc.w - tc.w;
    f[17] = sd.x - td.x; f[18] = sd.y - td.y; f[19] = sd.z - td.z; f[20] = sd.w - td.w;
    f[21] = 1.f;
    unsigned p[16];
#pragma unroll
    for (int j = 0; j < 11; j++) p[j] = pk(f[2 * j], f[2 * j + 1]);
#pragma unroll
    for (int j = 11; j < 16; j++) p[j] = 0u;
#pragma unroll
    for (int g = 0; g < 4; g++) {
        int byte = l * 64 + ((g ^ (l & 3)) << 4);
        u4 w; w.x = p[4 * g]; w.y = p[4 * g + 1]; w.z = p[4 * g + 2]; w.w = p[4 * g + 3];
        *(u4*)(lds + byte) = w;
    }
    __syncthreads();

    u4 B1[4];
#pragma unroll
    for (int n = 0; n < 4; n++) {
        int e = n * 16 + (l & 15);
        int byte = e * 64 + ((((l >> 4) & 3) ^ (e & 3)) << 4);
        B1[n] = *(const u4*)(lds + byte);
    }
    __syncthreads();

    f4 acc[4][4];
#pragma unroll
    for (int m = 0; m < 4; m++)
#pragma unroll
        for (int n = 0; n < 4; n++) { acc[m][n].x = 0.f; acc[m][n].y = 0.f; acc[m][n].z = 0.f; acc[m][n].w = 0.f; }

    const unsigned short* W1u = (const unsigned short*)W1b;
    const unsigned short* W2u = (const unsigned short*)W2b;
    const unsigned short* W3u = (const unsigned short*)W3b;
#pragma unroll
    for (int m = 0; m < 4; m++) {
        u4 w = *(const u4*)(W1u + (m * 16 + (l & 15)) * 32 + (l >> 4) * 8);
#pragma unroll
        for (int n = 0; n < 4; n++) MFMA(acc[m][n], w, B1[n]);
    }
    write_tiles(lds, l, acc, nullptr);
    __syncthreads();

    u4 B2[4][2];
#pragma unroll
    for (int n = 0; n < 4; n++)
#pragma unroll
        for (int ks = 0; ks < 2; ks++) {
            int e = n * 16 + (l & 15);
            int g = ks * 4 + (l >> 4);
            B2[n][ks] = *(const u4*)(lds + e * 128 + ((g ^ (e & 7)) << 4));
        }
    __syncthreads();
#pragma unroll
    for (int m = 0; m < 4; m++)
#pragma unroll
        for (int n = 0; n < 4; n++) { acc[m][n].x = 0.f; acc[m][n].y = 0.f; acc[m][n].z = 0.f; acc[m][n].w = 0.f; }
#pragma unroll
    for (int m = 0; m < 4; m++)
#pragma unroll
        for (int ks = 0; ks < 2; ks++) {
            u4 w = *(const u4*)(W2u + (m * 16 + (l & 15)) * 64 + ks * 32 + (l >> 4) * 8);
#pragma unroll
            for (int n = 0; n < 4; n++) MFMA(acc[m][n], w, B2[n][ks]);
        }
    write_tiles(lds, l, acc, mb2);
    __syncthreads();

#pragma unroll
    for (int n = 0; n < 4; n++)
#pragma unroll
        for (int ks = 0; ks < 2; ks++) {
            int e = n * 16 + (l & 15);
            int g = ks * 4 + (l >> 4);
            B2[n][ks] = *(const u4*)(lds + e * 128 + ((g ^ (e & 7)) << 4));
        }
    __syncthreads();
#pragma unroll
    for (int m = 0; m < 4; m++)
#pragma unroll
        for (int n = 0; n < 4; n++) { acc[m][n].x = 0.f; acc[m][n].y = 0.f; acc[m][n].z = 0.f; acc[m][n].w = 0.f; }
#pragma unroll
    for (int m = 0; m < 4; m++)
#pragma unroll
        for (int ks = 0; ks < 2; ks++) {
            u4 w = *(const u4*)(W3u + (m * 16 + (l & 15)) * 64 + ks * 32 + (l >> 4) * 8);
#pragma unroll
            for (int n = 0; n < 4; n++) MFMA(acc[m][n], w, B2[n][ks]);
        }
    write_tiles(lds, l, acc, mb3);
    __syncthreads();

#pragma unroll
    for (int it = 0; it < 8; it++) {
        int e = it * 8 + (l >> 3);
        int g = l & 7;
        u4 vv = *(const u4*)(lds + e * 128 + ((g ^ (e & 7)) << 4));
        *(u4*)((unsigned short*)msg + (size_t)(e0 + e) * 64 + g * 8) = vv;
    }
}

// ---------------------------------------------------------------- attention aggregate (edge loop only)
// agg[n][256] bf16 per head h (base h*128): [0..63]=Wm_h, [64..95]=Ws_h (a=0..31, slot 20 = S_h),
// [96..127]=S_h*sf (20 real + 12 zero). invp[n][2] = 1/(S_h+1e-16).
__global__ __launch_bounds__(256) void k_attn(
    const int* __restrict__ row_off, const int* __restrict__ src,
    const __hip_bfloat16* __restrict__ msg,
    const __hip_bfloat16* __restrict__ selffb, const float* __restrict__ qkp,
    const float* __restrict__ qwe, const float* __restrict__ selff,
    __hip_bfloat16* __restrict__ agg, float* __restrict__ invp)
{
    int tid = threadIdx.x, wid = tid >> 6, lane = tid & 63;
    int g = lane >> 4, c16 = lane & 15;
    int n = blockIdx.x * 4 + wid;

    f4 qm0 = *(const f4*)(qwe + n * 168 + 4 * c16);
    f4 qm1 = *(const f4*)(qwe + n * 168 + 84 + 4 * c16);
    float2 qk0 = *(const float2*)(qkp + n * 64 + 2 * c16);
    float2 qk1 = *(const float2*)(qkp + n * 64 + 32 + 2 * c16);

    float a00 = 0.f, a01 = 0.f;
#pragma unroll
    for (int j = 0; j < 20; j++) {
        float sfj = selff[n * 20 + j];
        a00 += sfj * qwe[n * 168 + 64 + j];
        a01 += sfj * qwe[n * 168 + 84 + 64 + j];
    }

    const unsigned short* msgu = (const unsigned short*)msg;
    const unsigned short* sfu  = (const unsigned short*)selffb;
    int r0 = row_off[n], r1 = row_off[n + 1];
    int nit = (r1 - r0 + 3) >> 2;

    f4 Wm0 = {0,0,0,0}, Wm1 = {0,0,0,0};
    float Ws00 = 0.f, Ws01 = 0.f, Ws10 = 0.f, Ws11 = 0.f;
    float S0 = 0.f, S1 = 0.f;

#pragma unroll 2
    for (int it = 0; it < nit; it++) {
        int e = r0 + it * 4 + g;
        bool ok = (e < r1);
        int ec = ok ? e : r0;
        int s = src[ec];
        ushort2 su = *(const ushort2*)(sfu + (size_t)s * 32 + 2 * c16);
        float sf0 = bf2f(su.x), sf1 = bf2f(su.y);
        f4 mc = bf2f4(*(const ushort4*)(msgu + (size_t)ec * 64 + 4 * c16));

        float t0 = dot4(qm0, mc) + sf0 * qk0.x + sf1 * qk0.y;
        float t1 = dot4(qm1, mc) + sf0 * qk1.x + sf1 * qk1.y;
#pragma unroll
        for (int mk = 1; mk < 16; mk <<= 1) {
            t0 += __shfl_xor(t0, mk, 64);
            t1 += __shfl_xor(t1, mk, 64);
        }
        float w0 = ok ? __expf((t0 + a00) * 0.125f) : 0.f;
        float w1 = ok ? __expf((t1 + a01) * 0.125f) : 0.f;
        S0 += w0; S1 += w1;
        fma4(Wm0, w0, mc); fma4(Wm1, w1, mc);
        Ws00 += w0 * sf0; Ws01 += w0 * sf1;
        Ws10 += w1 * sf0; Ws11 += w1 * sf1;
    }

    // cross-group butterfly: every lane ends with full-node totals for its channel slice
#pragma unroll
    for (int mk = 16; mk <= 32; mk <<= 1) {
        Wm0.x += __shfl_xor(Wm0.x, mk, 64); Wm0.y += __shfl_xor(Wm0.y, mk, 64);
        Wm0.z += __shfl_xor(Wm0.z, mk, 64); Wm0.w += __shfl_xor(Wm0.w, mk, 64);
        Wm1.x += __shfl_xor(Wm1.x, mk, 64); Wm1.y += __shfl_xor(Wm1.y, mk, 64);
        Wm1.z += __shfl_xor(Wm1.z, mk, 64); Wm1.w += __shfl_xor(Wm1.w, mk, 64);
        Ws00 += __shfl_xor(Ws00, mk, 64); Ws01 += __shfl_xor(Ws01, mk, 64);
        Ws10 += __shfl_xor(Ws10, mk, 64); Ws11 += __shfl_xor(Ws11, mk, 64);
        S0 += __shfl_xor(S0, mk, 64); S1 += __shfl_xor(S1, mk, 64);
    }

    unsigned short* arow = (unsigned short*)agg + (size_t)n * 256;
    if (g == 0) {
        uint2 w; w.x = pk(Wm0.x, Wm0.y); w.y = pk(Wm0.z, Wm0.w);
        *(uint2*)(arow + 4 * c16) = w;
        int j0 = 2 * c16, j1 = 2 * c16 + 1;
        float v0 = (j0 < 20) ? S0 * selff[n * 20 + j0] : 0.f;
        float v1 = (j1 < 20) ? S0 * selff[n * 20 + j1] : 0.f;
        *(unsigned*)(arow + 96 + 2 * c16) = pk(v0, v1);
    } else if (g == 1) {
        uint2 w; w.x = pk(Wm1.x, Wm1.y); w.y = pk(Wm1.z, Wm1.w);
        *(uint2*)(arow + 128 + 4 * c16) = w;
        int j0 = 2 * c16, j1 = 2 * c16 + 1;
        float v0 = (j0 < 20) ? S1 * selff[n * 20 + j0] : 0.f;
        float v1 = (j1 < 20) ? S1 * selff[n * 20 + j1] : 0.f;
        *(unsigned*)(arow + 128 + 96 + 2 * c16) = pk(v0, v1);
    } else if (g == 2) {
        *(unsigned*)(arow + 64 + 2 * c16) = pk(Ws00, Ws01);
        if (c16 == 0) invp[2 * n] = 1.f / (S0 + 1e-16f);
    } else {
        *(unsigned*)(arow + 128 + 64 + 2 * c16) = pk(Ws10, Ws11);
        if (c16 == 0) invp[2 * n + 1] = 1.f / (S1 + 1e-16f);
    }
}

// ---------------------------------------------------------------- fused attn-epilogue + final MLP (1 wave = 64 nodes)
// Stage-0 B fragments read DIRECTLY from global agg (no LDS staging).
__global__ __launch_bounds__(64) void k_final2(
    const __hip_bfloat16* __restrict__ agg, const float* __restrict__ invp,
    const float* __restrict__ skipf, const __hip_bfloat16* __restrict__ WcA,
    const __hip_bfloat16* __restrict__ H1b, const __hip_bfloat16* __restrict__ H2b,
    const __hip_bfloat16* __restrict__ H3b,
    const float* __restrict__ hb1, const float* __restrict__ hb2, const float* __restrict__ hb3,
    float* __restrict__ out)
{
    __shared__ char lds[64 * 128];
    int l = threadIdx.x;
    int n0 = blockIdx.x * 64;

    const unsigned short* aggU = (const unsigned short*)agg;
    const unsigned short* WcU = (const unsigned short*)WcA;
    const unsigned short* H1u = (const unsigned short*)H1b;
    const unsigned short* H2u = (const unsigned short*)H2b;
    const unsigned short* H3u = (const unsigned short*)H3b;

    int nodes[4];
    float inv0[4], inv1[4];
#pragma unroll
    for (int n4 = 0; n4 < 4; n4++) {
        int node = n0 + n4 * 16 + (l & 15); if (node >= NN) node = NN - 1;
        nodes[n4] = node;
        float2 iv = *(const float2*)(invp + 2 * node);
        inv0[n4] = iv.x; inv1[n4] = iv.y;
    }

    f4 osum[4][4];
#pragma unroll
    for (int m = 0; m < 4; m++)
#pragma unroll
        for (int n4 = 0; n4 < 4; n4++) { osum[m][n4].x = 0.f; osum[m][n4].y = 0.f; osum[m][n4].z = 0.f; osum[m][n4].w = 0.f; }

    // stage 0: per head, K=128 GEMM  D[ch][node] = Wc_h @ agg_h  (B from global)
#pragma unroll
    for (int h = 0; h < 2; h++) {
        f4 acc[4][4];
#pragma unroll
        for (int m = 0; m < 4; m++)
#pragma unroll
            for (int n4 = 0; n4 < 4; n4++) { acc[m][n4].x = 0.f; acc[m][n4].y = 0.f; acc[m][n4].z = 0.f; acc[m][n4].w = 0.f; }
#pragma unroll
        for (int ks = 0; ks < 4; ks++) {
            u4 A[4];
#pragma unroll
            for (int m = 0; m < 4; m++)
                A[m] = *(const u4*)(WcU + h * 8192 + (m * 16 + (l & 15)) * 128 + ks * 32 + (l >> 4) * 8);
#pragma unroll
            for (int n4 = 0; n4 < 4; n4++) {
                u4 B = *(const u4*)(aggU + (size_t)nodes[n4] * 256 + h * 128 + ks * 32 + (l >> 4) * 8);
#pragma unroll
                for (int m = 0; m < 4; m++) MFMA(acc[m][n4], A[m], B);
            }
        }
        const float* iv = h ? inv1 : inv0;
#pragma unroll
        for (int m = 0; m < 4; m++)
#pragma unroll
            for (int n4 = 0; n4 < 4; n4++) fma4(osum[m][n4], 0.5f * iv[n4], acc[m][n4]);
    }

    // add skip, pack into [64 nodes][64 ch] bf16 LDS tile (same layout as validated k_final_mfma)
#pragma unroll
    for (int m = 0; m < 4; m++) {
#pragma unroll
        for (int n4 = 0; n4 < 4; n4++) {
            int ch0 = m * 16 + ((l >> 4) << 2);
            float4 sk = *(const float4*)(skipf + (size_t)nodes[n4] * 64 + ch0);
            f4 v = osum[m][n4];
            float v0 = v.x + sk.x, v1 = v.y + sk.y, v2 = v.z + sk.z, v3 = v.w + sk.w;
            int e = n4 * 16 + (l & 15);
            int byte = e * 128 + ((((ch0 >> 3) ^ (e & 7))) << 4) + (ch0 & 7) * 2;
            uint2 w; w.x = pk(v0, v1); w.y = pk(v2, v3);
            *(uint2*)(lds + byte) = w;
        }
    }
    __syncthreads();

    u4 B[4][2];
    f4 acc[4][4];

    // ---- stage 1
#pragma unroll
    for (int n = 0; n < 4; n++)
#pragma unroll
        for (int ks = 0; ks < 2; ks++) {
            int e = n * 16 + (l & 15);
            int g = ks * 4 + (l >> 4);
            B[n][ks] = *(const u4*)(lds + e * 128 + ((g ^ (e & 7)) << 4));
        }
    __syncthreads();
#pragma unroll
    for (int m = 0; m < 4; m++)
#pragma unroll
        for (int n = 0; n < 4; n++) { acc[m][n].x = 0.f; acc[m][n].y = 0.f; acc[m][n].z = 0.f; acc[m][n].w = 0.f; }
#pragma unroll
    for (int m = 0; m < 4; m++)
#pragma unroll
        for (int ks = 0; ks < 2; ks++) {
            u4 w = *(const u4*)(H1u + (m * 16 + (l & 15)) * 64 + ks * 32 + (l >> 4) * 8);
#pragma unroll
            for (int n = 0; n < 4; n++) MFMA(acc[m][n], w, B[n][ks]);
        }
    write_tiles(lds, l, acc, hb1);
    __syncthreads();

    // ---- stage 2
#pragma unroll
    for (int n = 0; n < 4; n++)
#pragma unroll
        for (int ks = 0; ks < 2; ks++) {
            int e = n * 16 + (l & 15);
            int g = ks * 4 + (l >> 4);
            B[n][ks] = *(const u4*)(lds + e * 128 + ((g ^ (e & 7)) << 4));
        }
    __syncthreads();
#pragma unroll
    for (int m = 0; m < 4; m++)
#pragma unroll
        for (int n = 0; n < 4; n++) { acc[m][n].x = 0.f; acc[m][n].y = 0.f; acc[m][n].z = 0.f; acc[m][n].w = 0.f; }
#pragma unroll
    for (int m = 0; m < 4; m++)
#pragma unroll
        for (int ks = 0; ks < 2; ks++) {
            u4 w = *(const u4*)(H2u + (m * 16 + (l & 15)) * 64 + ks * 32 + (l >> 4) * 8);
#pragma unroll
            for (int n = 0; n < 4; n++) MFMA(acc[m][n], w, B[n][ks]);
        }
    write_tiles(lds, l, acc, hb2);
    __syncthreads();

    // ---- stage 3: 64 -> 20
#pragma unroll
    for (int n = 0; n < 4; n++)
#pragma unroll
        for (int ks = 0; ks < 2; ks++) {
            int e = n * 16 + (l & 15);
            int g = ks * 4 + (l >> 4);
            B[n][ks] = *(const u4*)(lds + e * 128 + ((g ^ (e & 7)) << 4));
        }

    f4 acc3[2][4];
#pragma unroll
    for (int m = 0; m < 2; m++)
#pragma unroll
        for (int n = 0; n < 4; n++) { acc3[m][n].x = 0.f; acc3[m][n].y = 0.f; acc3[m][n].z = 0.f; acc3[m][n].w = 0.f; }
#pragma unroll
    for (int m = 0; m < 2; m++)
#pragma unroll
        for (int ks = 0; ks < 2; ks++) {
            u4 w = *(const u4*)(H3u + (m * 16 + (l & 15)) * 64 + ks * 32 + (l >> 4) * 8);
#pragma unroll
            for (int n = 0; n < 4; n++) MFMA(acc3[m][n], w, B[n][ks]);
        }

#pragma unroll
    for (int m = 0; m < 2; m++) {
#pragma unroll
        for (int j = 0; j < 4; j++) {
            int ch = m * 16 + (l >> 4) * 4 + j;
            if (ch < 20) {
                float b = hb3[ch];
#pragma unroll
                for (int nt = 0; nt < 4; nt++) {
                    int node = n0 + nt * 16 + (l & 15);
                    if (node < NN) {
                        float v = acc3[m][nt][j] + b;
                        if (ch < 2)       out[node * 2 + ch] = v;
                        else if (ch == 2) out[2 * NN + node] = v;
                        else if (ch < 19) out[3 * NN + node * 16 + (ch - 3)] = v;
                        else              out[19 * NN + node] = v;
                    }
                }
            }
        }
    }
}

// ---------------------------------------------------------------- launch
extern "C" void kernel_launch(void* const* d_in, const int* in_sizes, int n_in,
                              void* d_out, int out_size, void* d_ws, size_t ws_size,
                              hipStream_t stream)
{
    const float* x      = (const float*)d_in[0];
    const float* angle  = (const float*)d_in[1];
    const float* mol    = (const float*)d_in[2];
    const float* gen    = (const float*)d_in[3];
    const int*   src    = (const int*)d_in[4];
    const int*   dst    = (const int*)d_in[5];
    const float* mask   = (const float*)d_in[6];
    const float* mw1    = (const float*)d_in[7];
    const float* mb1    = (const float*)d_in[8];
    const float* mw2    = (const float*)d_in[9];
    const float* mb2    = (const float*)d_in[10];
    const float* mw3    = (const float*)d_in[11];
    const float* mb3    = (const float*)d_in[12];
    const float* wq     = (const float*)d_in[13];
    const float* bq     = (const float*)d_in[14];
    const float* wk     = (const float*)d_in[15];
    const float* bk     = (const float*)d_in[16];
    const float* wv     = (const float*)d_in[17];
    const float* bv     = (const float*)d_in[18];
    const float* we     = (const float*)d_in[19];
    const float* wskip  = (const float*)d_in[20];
    const float* bskip  = (const float*)d_in[21];
    const float* hw1    = (const float*)d_in[22];
    const float* hb1    = (const float*)d_in[23];
    const float* hw2    = (const float*)d_in[24];
    const float* hb2    = (const float*)d_in[25];
    const float* hw3    = (const float*)d_in[26];
    const float* hb3    = (const float*)d_in[27];
    float* out = (float*)d_out;

    char* p = (char*)d_ws;
    auto alloc = [&](size_t bytes) -> void* {
        void* r = (void*)p;
        p += (bytes + 255) & ~(size_t)255;
        return r;
    };
    int*   row_off = (int*)alloc((NN + 1) * 4);
    float* selff   = (float*)alloc((size_t)NN * 20 * 4);
    __hip_bfloat16* selffb = (__hip_bfloat16*)alloc((size_t)NN * 32 * 2);
    float* qkp     = (float*)alloc((size_t)NN * 64 * 4);
    float* skipf   = (float*)alloc((size_t)NN * 64 * 4);
    float* qwe     = (float*)alloc((size_t)NN * 168 * 4);
    __hip_bfloat16* agg = (__hip_bfloat16*)alloc((size_t)NN * 256 * 2);
    float* invp    = (float*)alloc((size_t)NN * 2 * 4);
    __hip_bfloat16* W1b = (__hip_bfloat16*)alloc(2048 * 2);
    __hip_bfloat16* W2b = (__hip_bfloat16*)alloc(4096 * 2);
    __hip_bfloat16* W3b = (__hip_bfloat16*)alloc(4096 * 2);
    __hip_bfloat16* H1b = (__hip_bfloat16*)alloc(4096 * 2);
    __hip_bfloat16* H2b = (__hip_bfloat16*)alloc(4096 * 2);
    __hip_bfloat16* H3b = (__hip_bfloat16*)alloc(2048 * 2);
    float* weT     = (float*)alloc(10752 * 4);
    float* wkT     = (float*)alloc(4096 * 4);
    __hip_bfloat16* WcA = (__hip_bfloat16*)alloc(16384 * 2);
    __hip_bfloat16* msg = (__hip_bfloat16*)alloc((size_t)EF * 64 * 2);

    k_prep<<<202, 256, 0, stream>>>(mw1, mb1, mw2, mw3, hw1, hw2, hw3, we, wk, bk, wv, bv,
                                    W1b, W2b, W3b, H1b, H2b, H3b, weT, wkT, WcA);
    k_csr<<<(NN + 256) / 256, 256, 0, stream>>>(dst, mask, row_off);
    k_node<<<NN / 4, 256, 0, stream>>>(angle, mol, gen, row_off, wq, bq,
                                       wskip, bskip, weT, wkT,
                                       selff, selffb, skipf, qwe, qkp);
    k_edge_mfma<<<(EF / 64 + 3) / 4, 256, 0, stream>>>(x, angle, mol, src, dst,
                                                       W1b, W2b, W3b, mb2, mb3, msg);
    k_attn<<<NN / 4, 256, 0, stream>>>(row_off, src, msg, selffb, qkp,
                                       qwe, selff, agg, invp);
    k_final2<<<(NN + 63) / 64, 64, 0, stream>>>(agg, invp, skipf, WcA,
                                                H1b, H2b, H3b, hb1, hb2, hb3, out);
}

// Round 10
// 152.637 us; speedup vs baseline: 1.4366x; 1.2049x over previous
//
#include <hip/hip_runtime.h>
#include <hip/hip_bf16.h>
#include <math.h>

#define NN 20000
#define EF 720000

typedef float  f4 __attribute__((ext_vector_type(4)));
typedef unsigned int u4 __attribute__((ext_vector_type(4)));

__device__ __forceinline__ void MFMA(f4& c, u4 a, u4 b) {
    asm("v_mfma_f32_16x16x32_bf16 %0, %1, %2, %0" : "+v"(c) : "v"(a), "v"(b));
}

__device__ __forceinline__ unsigned pk(float a, float b) {
    __hip_bfloat162 t = __halves2bfloat162(__float2bfloat16(a), __float2bfloat16(b));
    unsigned u; __builtin_memcpy(&u, &t, 4); return u;
}
__device__ __forceinline__ float bf2f(unsigned short u) {
    return __builtin_bit_cast(float, (unsigned)u << 16);
}
__device__ __forceinline__ f4 bf2f4(ushort4 u) {
    f4 r; r.x = bf2f(u.x); r.y = bf2f(u.y); r.z = bf2f(u.z); r.w = bf2f(u.w); return r;
}
__device__ __forceinline__ float dot4(f4 a, f4 b) {
    return a.x * b.x + a.y * b.y + a.z * b.z + a.w * b.w;
}
__device__ __forceinline__ void fma4(f4& acc, float w, f4 v) {
    acc.x += w * v.x; acc.y += w * v.y; acc.z += w * v.z; acc.w += w * v.w;
}

// ---------------------------------------------------------------- prep: bf16 weights + composed projections
// WcA[h][ch][k], K=128: k<64 -> we[k][h*64+ch]; 64..83 -> wv[k-64]; 84 -> bv; 85..95 -> 0;
//                       96..115 -> we[64+(k-96)]; 116..127 -> 0
// Mwe[j][o], j=0..20 (j=20 = bq row), o = h*84+a: sum_c wqa[j][h*64+c]*we[a][h*64+c]
// Mk[j][o],  o = h*32+a (a<=20 real, a=20 via bk): sum_c wqa[j][h*64+c]*wka[a][h*64+c]
__global__ __launch_bounds__(256) void k_prep(
    const float* __restrict__ mw1, const float* __restrict__ mb1,
    const float* __restrict__ mw2, const float* __restrict__ mw3,
    const float* __restrict__ hw1, const float* __restrict__ hw2, const float* __restrict__ hw3,
    const float* __restrict__ we, const float* __restrict__ wk, const float* __restrict__ bk,
    const float* __restrict__ wv, const float* __restrict__ bv,
    const float* __restrict__ wq, const float* __restrict__ bq,
    __hip_bfloat16* __restrict__ W1b, __hip_bfloat16* __restrict__ W2b, __hip_bfloat16* __restrict__ W3b,
    __hip_bfloat16* __restrict__ H1b, __hip_bfloat16* __restrict__ H2b, __hip_bfloat16* __restrict__ H3b,
    __hip_bfloat16* __restrict__ WcA, float* __restrict__ Mwe, float* __restrict__ Mk)
{
    int t = blockIdx.x * 256 + threadIdx.x;
    if (t < 2048) {  // W1b[ch][k], K=32: k<21 weights, k==21 bias, rest 0
        int ch = t >> 5, k = t & 31;
        float v = (k < 21) ? mw1[k * 64 + ch] : (k == 21 ? mb1[ch] : 0.f);
        W1b[t] = __float2bfloat16(v); return;
    }
    t -= 2048;
    if (t < 4096) { int ch = t >> 6, k = t & 63; W2b[t] = __float2bfloat16(mw2[k * 64 + ch]); return; }
    t -= 4096;
    if (t < 4096) { int ch = t >> 6, k = t & 63; W3b[t] = __float2bfloat16(mw3[k * 64 + ch]); return; }
    t -= 4096;
    if (t < 4096) { int ch = t >> 6, k = t & 63; H1b[t] = __float2bfloat16(hw1[k * 64 + ch]); return; }
    t -= 4096;
    if (t < 4096) { int ch = t >> 6, k = t & 63; H2b[t] = __float2bfloat16(hw2[k * 64 + ch]); return; }
    t -= 4096;
    if (t < 2048) {  // H3b padded to 32 rows
        int ch = t >> 6, k = t & 63;
        float v = (ch < 20) ? hw3[k * 20 + ch] : 0.f;
        H3b[t] = __float2bfloat16(v); return;
    }
    t -= 2048;
    if (t < 16384) {
        int h = t >> 13, rem = t & 8191;
        int ch = rem >> 7, k = rem & 127;
        int col = h * 64 + ch;
        float v;
        if (k < 64)        v = we[k * 128 + col];
        else if (k < 84)   v = wv[(k - 64) * 128 + col];
        else if (k == 84)  v = bv[col];
        else if (k < 96)   v = 0.f;
        else if (k < 116)  v = we[(64 + (k - 96)) * 128 + col];
        else               v = 0.f;
        WcA[t] = __float2bfloat16(v); return;
    }
    t -= 16384;
    if (t < 3528) {  // Mwe: 21 x 168
        int j = t / 168, o = t % 168;
        int h = (o >= 84) ? 1 : 0, a = o - 84 * h;
        float acc = 0.f;
        for (int c = 0; c < 64; c++) {
            int hc = h * 64 + c;
            float wqv = (j < 20) ? wq[j * 128 + hc] : bq[hc];
            acc += wqv * we[a * 128 + hc];
        }
        Mwe[t] = acc; return;
    }
    t -= 3528;
    if (t < 1344) {  // Mk: 21 x 64
        int j = t / 64, rem = t % 64;
        int h = rem >> 5, a = rem & 31;
        float acc = 0.f;
        if (a <= 20) {
            for (int c = 0; c < 64; c++) {
                int hc = h * 64 + c;
                float wqv = (j < 20) ? wq[j * 128 + hc] : bq[hc];
                float wkv = (a < 20) ? wk[a * 128 + hc] : bk[hc];
                acc += wqv * wkv;
            }
        }
        Mk[t] = acc; return;
    }
}

// ---------------------------------------------------------------- CSR via binary search
__global__ __launch_bounds__(256) void k_csr(
    const int* __restrict__ dst, const float* __restrict__ mask, int* __restrict__ row_off)
{
    int n = blockIdx.x * 256 + threadIdx.x;
    if (n > NN) return;
    int lo = 0, hi = EF;
    while (lo < hi) { int mid = (lo + hi) >> 1; if (mask[mid] > 0.5f) lo = mid + 1; else hi = mid; }
    int Ea = lo;
    lo = 0; hi = Ea;
    while (lo < hi) { int mid = (lo + hi) >> 1; if (dst[mid] < n) lo = mid + 1; else hi = mid; }
    row_off[n] = lo;
}

// ---------------------------------------------------------------- node features + composed projections (L1-hot tables)
__global__ __launch_bounds__(256) void k_node(
    const float* __restrict__ angle, const float* __restrict__ mol, const float* __restrict__ gen,
    const int* __restrict__ row_off,
    const float* __restrict__ wskip, const float* __restrict__ bskip,
    const float* __restrict__ Mwe, const float* __restrict__ Mk,
    float* __restrict__ selff, __hip_bfloat16* __restrict__ selffb,
    float* __restrict__ skipf, float* __restrict__ qwe, float* __restrict__ qkp)
{
    int wid = threadIdx.x >> 6, lane = threadIdx.x & 63;
    int n = blockIdx.x * 4 + wid;

    float an = angle[n];
    float sv, cv; sincosf(an, &sv, &cv);
    float degf = (float)(row_off[n + 1] - row_off[n]);
    float sfa[21];
    sfa[0] = sv; sfa[1] = cv;
#pragma unroll
    for (int j = 0; j < 16; j++) sfa[2 + j] = mol[n * 16 + j];
    sfa[18] = gen[n];
    sfa[19] = degf;
    sfa[20] = 1.f;

    float sval = (lane == 0) ? sv : (lane == 1) ? cv :
                 (lane < 18) ? mol[n * 16 + (lane - 2)] :
                 (lane == 18) ? gen[n] : degf;
    if (lane < 20) selff[n * 20 + lane] = sval;
    if (lane < 32) {
        float v = (lane < 20) ? sval : (lane == 20 ? 1.f : 0.f);
        selffb[n * 32 + lane] = __float2bfloat16(v);
    }

    // skip projection (K=20 + bias)
    float sk = bskip[lane];
#pragma unroll
    for (int j = 0; j < 20; j++) sk += sfa[j] * wskip[j * 64 + lane];
    skipf[n * 64 + lane] = sk;

    // qwe[n][o] = sfa @ Mwe (o = h*84+a), coalesced over o, table L1-hot
#pragma unroll
    for (int r = 0; r < 3; r++) {
        int o = r * 64 + lane;
        if (o < 168) {
            float acc = 0.f;
#pragma unroll
            for (int j = 0; j < 21; j++) acc += sfa[j] * Mwe[j * 168 + o];
            qwe[n * 168 + o] = acc;
        }
    }

    // qkp[n][o] = sfa @ Mk (o = h*32+a, bias slot a=20 folded in)
    {
        float acc = 0.f;
#pragma unroll
        for (int j = 0; j < 21; j++) acc += sfa[j] * Mk[j * 64 + lane];
        qkp[n * 64 + lane] = acc;
    }
}

// ---------------------------------------------------------------- edge MLP via MFMA (wave = 64 edges, 4 waves/block)
__device__ __forceinline__ void write_tiles(char* lds, int l, f4 (&acc)[4][4], const float* bias)
{
#pragma unroll
    for (int m = 0; m < 4; m++) {
        f4 bv;
        if (bias) bv = *(const f4*)(bias + m * 16 + ((l >> 4) << 2));
        else      { bv.x = 0.f; bv.y = 0.f; bv.z = 0.f; bv.w = 0.f; }
#pragma unroll
        for (int n = 0; n < 4; n++) {
            f4 v = acc[m][n];
            float v0 = fmaxf(v.x + bv.x, 0.f);
            float v1 = fmaxf(v.y + bv.y, 0.f);
            float v2 = fmaxf(v.z + bv.z, 0.f);
            float v3 = fmaxf(v.w + bv.w, 0.f);
            int e   = n * 16 + (l & 15);
            int ch0 = m * 16 + ((l >> 4) << 2);
            int byte = e * 128 + ((((ch0 >> 3) ^ (e & 7))) << 4) + (ch0 & 7) * 2;
            uint2 w; w.x = pk(v0, v1); w.y = pk(v2, v3);
            *(uint2*)(lds + byte) = w;
        }
    }
}

__global__ __launch_bounds__(256) void k_edge_mfma(
    const float* __restrict__ x, const float* __restrict__ angle, const float* __restrict__ mol,
    const int* __restrict__ src, const int* __restrict__ dst,
    const __hip_bfloat16* __restrict__ W1b, const __hip_bfloat16* __restrict__ W2b,
    const __hip_bfloat16* __restrict__ W3b,
    const float* __restrict__ mb2, const float* __restrict__ mb3,
    __hip_bfloat16* __restrict__ msg)
{
    __shared__ char lds_all[4][64 * 128];
    int wv = threadIdx.x >> 6, l = threadIdx.x & 63;
    char* lds = lds_all[wv];
    int e0 = (blockIdx.x * 4 + wv) * 64;
    if (e0 + 64 > EF) e0 = EF - 64;

    int s = src[e0 + l], d = dst[e0 + l];
    float2 xs = ((const float2*)x)[s], xd = ((const float2*)x)[d];
    float dx = xs.x - xd.x, dy = xs.y - xd.y;
    float r = sqrtf(fmaxf(dx * dx + dy * dy, 1e-12f));
    float da = angle[s] - angle[d];
    float sv, cv; sincosf(da, &sv, &cv);
    const float4* m4 = (const float4*)mol;
    float4 sa = m4[s * 4 + 0], sb = m4[s * 4 + 1], sc = m4[s * 4 + 2], sd = m4[s * 4 + 3];
    float4 ta = m4[d * 4 + 0], tb = m4[d * 4 + 1], tc = m4[d * 4 + 2], td = m4[d * 4 + 3];
    float f[22];
    f[0] = dx; f[1] = dy; f[2] = r; f[3] = sv; f[4] = cv;
    f[5]  = sa.x - ta.x; f[6]  = sa.y - ta.y; f[7]  = sa.z - ta.z; f[8]  = sa.w - ta.w;
    f[9]  = sb.x - tb.x; f[10] = sb.y - tb.y; f[11] = sb.z - tb.z; f[12] = sb.w - tb.w;
    f[13] = sc.x - tc.x; f[14] = sc.y - tc.y; f[15] = sc.z - tc.z; f[16] = sc.w - tc.w;
    f[17] = sd.x - td.x; f[18] = sd.y - td.y; f[19] = sd.z - td.z; f[20] = sd.w - td.w;
    f[21] = 1.f;
    unsigned p[16];
#pragma unroll
    for (int j = 0; j < 11; j++) p[j] = pk(f[2 * j], f[2 * j + 1]);
#pragma unroll
    for (int j = 11; j < 16; j++) p[j] = 0u;
#pragma unroll
    for (int g = 0; g < 4; g++) {
        int byte = l * 64 + ((g ^ (l & 3)) << 4);
        u4 w; w.x = p[4 * g]; w.y = p[4 * g + 1]; w.z = p[4 * g + 2]; w.w = p[4 * g + 3];
        *(u4*)(lds + byte) = w;
    }
    __syncthreads();

    u4 B1[4];
#pragma unroll
    for (int n = 0; n < 4; n++) {
        int e = n * 16 + (l & 15);
        int byte = e * 64 + ((((l >> 4) & 3) ^ (e & 3)) << 4);
        B1[n] = *(const u4*)(lds + byte);
    }
    __syncthreads();

    f4 acc[4][4];
#pragma unroll
    for (int m = 0; m < 4; m++)
#pragma unroll
        for (int n = 0; n < 4; n++) { acc[m][n].x = 0.f; acc[m][n].y = 0.f; acc[m][n].z = 0.f; acc[m][n].w = 0.f; }

    const unsigned short* W1u = (const unsigned short*)W1b;
    const unsigned short* W2u = (const unsigned short*)W2b;
    const unsigned short* W3u = (const unsigned short*)W3b;
#pragma unroll
    for (int m = 0; m < 4; m++) {
        u4 w = *(const u4*)(W1u + (m * 16 + (l & 15)) * 32 + (l >> 4) * 8);
#pragma unroll
        for (int n = 0; n < 4; n++) MFMA(acc[m][n], w, B1[n]);
    }
    write_tiles(lds, l, acc, nullptr);
    __syncthreads();

    u4 B2[4][2];
#pragma unroll
    for (int n = 0; n < 4; n++)
#pragma unroll
        for (int ks = 0; ks < 2; ks++) {
            int e = n * 16 + (l & 15);
            int g = ks * 4 + (l >> 4);
            B2[n][ks] = *(const u4*)(lds + e * 128 + ((g ^ (e & 7)) << 4));
        }
    __syncthreads();
#pragma unroll
    for (int m = 0; m < 4; m++)
#pragma unroll
        for (int n = 0; n < 4; n++) { acc[m][n].x = 0.f; acc[m][n].y = 0.f; acc[m][n].z = 0.f; acc[m][n].w = 0.f; }
#pragma unroll
    for (int m = 0; m < 4; m++)
#pragma unroll
        for (int ks = 0; ks < 2; ks++) {
            u4 w = *(const u4*)(W2u + (m * 16 + (l & 15)) * 64 + ks * 32 + (l >> 4) * 8);
#pragma unroll
            for (int n = 0; n < 4; n++) MFMA(acc[m][n], w, B2[n][ks]);
        }
    write_tiles(lds, l, acc, mb2);
    __syncthreads();

#pragma unroll
    for (int n = 0; n < 4; n++)
#pragma unroll
        for (int ks = 0; ks < 2; ks++) {
            int e = n * 16 + (l & 15);
            int g = ks * 4 + (l >> 4);
            B2[n][ks] = *(const u4*)(lds + e * 128 + ((g ^ (e & 7)) << 4));
        }
    __syncthreads();
#pragma unroll
    for (int m = 0; m < 4; m++)
#pragma unroll
        for (int n = 0; n < 4; n++) { acc[m][n].x = 0.f; acc[m][n].y = 0.f; acc[m][n].z = 0.f; acc[m][n].w = 0.f; }
#pragma unroll
    for (int m = 0; m < 4; m++)
#pragma unroll
        for (int ks = 0; ks < 2; ks++) {
            u4 w = *(const u4*)(W3u + (m * 16 + (l & 15)) * 64 + ks * 32 + (l >> 4) * 8);
#pragma unroll
            for (int n = 0; n < 4; n++) MFMA(acc[m][n], w, B2[n][ks]);
        }
    write_tiles(lds, l, acc, mb3);
    __syncthreads();

#pragma unroll
    for (int it = 0; it < 8; it++) {
        int e = it * 8 + (l >> 3);
        int g = l & 7;
        u4 vv = *(const u4*)(lds + e * 128 + ((g ^ (e & 7)) << 4));
        *(u4*)((unsigned short*)msg + (size_t)(e0 + e) * 64 + g * 8) = vv;
    }
}

// ---------------------------------------------------------------- attention aggregate (edge loop only)
// agg[n][256] bf16 per head h (base h*128): [0..63]=Wm_h, [64..95]=Ws_h (a=0..31, slot 20 = S_h),
// [96..127]=S_h*sf (20 real + 12 zero). invp[n][2] = 1/(S_h+1e-16).
__global__ __launch_bounds__(256) void k_attn(
    const int* __restrict__ row_off, const int* __restrict__ src,
    const __hip_bfloat16* __restrict__ msg,
    const __hip_bfloat16* __restrict__ selffb, const float* __restrict__ qkp,
    const float* __restrict__ qwe, const float* __restrict__ selff,
    __hip_bfloat16* __restrict__ agg, float* __restrict__ invp)
{
    int tid = threadIdx.x, wid = tid >> 6, lane = tid & 63;
    int g = lane >> 4, c16 = lane & 15;
    int n = blockIdx.x * 4 + wid;

    f4 qm0 = *(const f4*)(qwe + n * 168 + 4 * c16);
    f4 qm1 = *(const f4*)(qwe + n * 168 + 84 + 4 * c16);
    float2 qk0 = *(const float2*)(qkp + n * 64 + 2 * c16);
    float2 qk1 = *(const float2*)(qkp + n * 64 + 32 + 2 * c16);

    float a00 = 0.f, a01 = 0.f;
#pragma unroll
    for (int j = 0; j < 20; j++) {
        float sfj = selff[n * 20 + j];
        a00 += sfj * qwe[n * 168 + 64 + j];
        a01 += sfj * qwe[n * 168 + 84 + 64 + j];
    }

    const unsigned short* msgu = (const unsigned short*)msg;
    const unsigned short* sfu  = (const unsigned short*)selffb;
    int r0 = row_off[n], r1 = row_off[n + 1];
    int nit = (r1 - r0 + 3) >> 2;

    f4 Wm0 = {0,0,0,0}, Wm1 = {0,0,0,0};
    float Ws00 = 0.f, Ws01 = 0.f, Ws10 = 0.f, Ws11 = 0.f;
    float S0 = 0.f, S1 = 0.f;

#pragma unroll 2
    for (int it = 0; it < nit; it++) {
        int e = r0 + it * 4 + g;
        bool ok = (e < r1);
        int ec = ok ? e : r0;
        int s = src[ec];
        ushort2 su = *(const ushort2*)(sfu + (size_t)s * 32 + 2 * c16);
        float sf0 = bf2f(su.x), sf1 = bf2f(su.y);
        f4 mc = bf2f4(*(const ushort4*)(msgu + (size_t)ec * 64 + 4 * c16));

        float t0 = dot4(qm0, mc) + sf0 * qk0.x + sf1 * qk0.y;
        float t1 = dot4(qm1, mc) + sf0 * qk1.x + sf1 * qk1.y;
#pragma unroll
        for (int mk = 1; mk < 16; mk <<= 1) {
            t0 += __shfl_xor(t0, mk, 64);
            t1 += __shfl_xor(t1, mk, 64);
        }
        float w0 = ok ? __expf((t0 + a00) * 0.125f) : 0.f;
        float w1 = ok ? __expf((t1 + a01) * 0.125f) : 0.f;
        S0 += w0; S1 += w1;
        fma4(Wm0, w0, mc); fma4(Wm1, w1, mc);
        Ws00 += w0 * sf0; Ws01 += w0 * sf1;
        Ws10 += w1 * sf0; Ws11 += w1 * sf1;
    }

    // cross-group butterfly: every lane ends with full-node totals for its channel slice
#pragma unroll
    for (int mk = 16; mk <= 32; mk <<= 1) {
        Wm0.x += __shfl_xor(Wm0.x, mk, 64); Wm0.y += __shfl_xor(Wm0.y, mk, 64);
        Wm0.z += __shfl_xor(Wm0.z, mk, 64); Wm0.w += __shfl_xor(Wm0.w, mk, 64);
        Wm1.x += __shfl_xor(Wm1.x, mk, 64); Wm1.y += __shfl_xor(Wm1.y, mk, 64);
        Wm1.z += __shfl_xor(Wm1.z, mk, 64); Wm1.w += __shfl_xor(Wm1.w, mk, 64);
        Ws00 += __shfl_xor(Ws00, mk, 64); Ws01 += __shfl_xor(Ws01, mk, 64);
        Ws10 += __shfl_xor(Ws10, mk, 64); Ws11 += __shfl_xor(Ws11, mk, 64);
        S0 += __shfl_xor(S0, mk, 64); S1 += __shfl_xor(S1, mk, 64);
    }

    unsigned short* arow = (unsigned short*)agg + (size_t)n * 256;
    if (g == 0) {
        uint2 w; w.x = pk(Wm0.x, Wm0.y); w.y = pk(Wm0.z, Wm0.w);
        *(uint2*)(arow + 4 * c16) = w;
        int j0 = 2 * c16, j1 = 2 * c16 + 1;
        float v0 = (j0 < 20) ? S0 * selff[n * 20 + j0] : 0.f;
        float v1 = (j1 < 20) ? S0 * selff[n * 20 + j1] : 0.f;
        *(unsigned*)(arow + 96 + 2 * c16) = pk(v0, v1);
    } else if (g == 1) {
        uint2 w; w.x = pk(Wm1.x, Wm1.y); w.y = pk(Wm1.z, Wm1.w);
        *(uint2*)(arow + 128 + 4 * c16) = w;
        int j0 = 2 * c16, j1 = 2 * c16 + 1;
        float v0 = (j0 < 20) ? S1 * selff[n * 20 + j0] : 0.f;
        float v1 = (j1 < 20) ? S1 * selff[n * 20 + j1] : 0.f;
        *(unsigned*)(arow + 128 + 96 + 2 * c16) = pk(v0, v1);
    } else if (g == 2) {
        *(unsigned*)(arow + 64 + 2 * c16) = pk(Ws00, Ws01);
        if (c16 == 0) invp[2 * n] = 1.f / (S0 + 1e-16f);
    } else {
        *(unsigned*)(arow + 128 + 64 + 2 * c16) = pk(Ws10, Ws11);
        if (c16 == 0) invp[2 * n + 1] = 1.f / (S1 + 1e-16f);
    }
}

// ---------------------------------------------------------------- fused attn-epilogue + final MLP (1 wave = 64 nodes)
// Stage-0 B fragments read DIRECTLY from global agg (no LDS staging).
__global__ __launch_bounds__(64) void k_final2(
    const __hip_bfloat16* __restrict__ agg, const float* __restrict__ invp,
    const float* __restrict__ skipf, const __hip_bfloat16* __restrict__ WcA,
    const __hip_bfloat16* __restrict__ H1b, const __hip_bfloat16* __restrict__ H2b,
    const __hip_bfloat16* __restrict__ H3b,
    const float* __restrict__ hb1, const float* __restrict__ hb2, const float* __restrict__ hb3,
    float* __restrict__ out)
{
    __shared__ char lds[64 * 128];
    int l = threadIdx.x;
    int n0 = blockIdx.x * 64;

    const unsigned short* aggU = (const unsigned short*)agg;
    const unsigned short* WcU = (const unsigned short*)WcA;
    const unsigned short* H1u = (const unsigned short*)H1b;
    const unsigned short* H2u = (const unsigned short*)H2b;
    const unsigned short* H3u = (const unsigned short*)H3b;

    int nodes[4];
    float inv0[4], inv1[4];
#pragma unroll
    for (int n4 = 0; n4 < 4; n4++) {
        int node = n0 + n4 * 16 + (l & 15); if (node >= NN) node = NN - 1;
        nodes[n4] = node;
        float2 iv = *(const float2*)(invp + 2 * node);
        inv0[n4] = iv.x; inv1[n4] = iv.y;
    }

    f4 osum[4][4];
#pragma unroll
    for (int m = 0; m < 4; m++)
#pragma unroll
        for (int n4 = 0; n4 < 4; n4++) { osum[m][n4].x = 0.f; osum[m][n4].y = 0.f; osum[m][n4].z = 0.f; osum[m][n4].w = 0.f; }

    // stage 0: per head, K=128 GEMM  D[ch][node] = Wc_h @ agg_h  (B from global)
#pragma unroll
    for (int h = 0; h < 2; h++) {
        f4 acc[4][4];
#pragma unroll
        for (int m = 0; m < 4; m++)
#pragma unroll
            for (int n4 = 0; n4 < 4; n4++) { acc[m][n4].x = 0.f; acc[m][n4].y = 0.f; acc[m][n4].z = 0.f; acc[m][n4].w = 0.f; }
#pragma unroll
        for (int ks = 0; ks < 4; ks++) {
            u4 A[4];
#pragma unroll
            for (int m = 0; m < 4; m++)
                A[m] = *(const u4*)(WcU + h * 8192 + (m * 16 + (l & 15)) * 128 + ks * 32 + (l >> 4) * 8);
#pragma unroll
            for (int n4 = 0; n4 < 4; n4++) {
                u4 B = *(const u4*)(aggU + (size_t)nodes[n4] * 256 + h * 128 + ks * 32 + (l >> 4) * 8);
#pragma unroll
                for (int m = 0; m < 4; m++) MFMA(acc[m][n4], A[m], B);
            }
        }
        const float* iv = h ? inv1 : inv0;
#pragma unroll
        for (int m = 0; m < 4; m++)
#pragma unroll
            for (int n4 = 0; n4 < 4; n4++) fma4(osum[m][n4], 0.5f * iv[n4], acc[m][n4]);
    }

    // add skip, pack into [64 nodes][64 ch] bf16 LDS tile
#pragma unroll
    for (int m = 0; m < 4; m++) {
#pragma unroll
        for (int n4 = 0; n4 < 4; n4++) {
            int ch0 = m * 16 + ((l >> 4) << 2);
            float4 sk = *(const float4*)(skipf + (size_t)nodes[n4] * 64 + ch0);
            f4 v = osum[m][n4];
            float v0 = v.x + sk.x, v1 = v.y + sk.y, v2 = v.z + sk.z, v3 = v.w + sk.w;
            int e = n4 * 16 + (l & 15);
            int byte = e * 128 + ((((ch0 >> 3) ^ (e & 7))) << 4) + (ch0 & 7) * 2;
            uint2 w; w.x = pk(v0, v1); w.y = pk(v2, v3);
            *(uint2*)(lds + byte) = w;
        }
    }
    __syncthreads();

    u4 B[4][2];
    f4 acc[4][4];

    // ---- stage 1
#pragma unroll
    for (int n = 0; n < 4; n++)
#pragma unroll
        for (int ks = 0; ks < 2; ks++) {
            int e = n * 16 + (l & 15);
            int g = ks * 4 + (l >> 4);
            B[n][ks] = *(const u4*)(lds + e * 128 + ((g ^ (e & 7)) << 4));
        }
    __syncthreads();
#pragma unroll
    for (int m = 0; m < 4; m++)
#pragma unroll
        for (int n = 0; n < 4; n++) { acc[m][n].x = 0.f; acc[m][n].y = 0.f; acc[m][n].z = 0.f; acc[m][n].w = 0.f; }
#pragma unroll
    for (int m = 0; m < 4; m++)
#pragma unroll
        for (int ks = 0; ks < 2; ks++) {
            u4 w = *(const u4*)(H1u + (m * 16 + (l & 15)) * 64 + ks * 32 + (l >> 4) * 8);
#pragma unroll
            for (int n = 0; n < 4; n++) MFMA(acc[m][n], w, B[n][ks]);
        }
    write_tiles(lds, l, acc, hb1);
    __syncthreads();

    // ---- stage 2
#pragma unroll
    for (int n = 0; n < 4; n++)
#pragma unroll
        for (int ks = 0; ks < 2; ks++) {
            int e = n * 16 + (l & 15);
            int g = ks * 4 + (l >> 4);
            B[n][ks] = *(const u4*)(lds + e * 128 + ((g ^ (e & 7)) << 4));
        }
    __syncthreads();
#pragma unroll
    for (int m = 0; m < 4; m++)
#pragma unroll
        for (int n = 0; n < 4; n++) { acc[m][n].x = 0.f; acc[m][n].y = 0.f; acc[m][n].z = 0.f; acc[m][n].w = 0.f; }
#pragma unroll
    for (int m = 0; m < 4; m++)
#pragma unroll
        for (int ks = 0; ks < 2; ks++) {
            u4 w = *(const u4*)(H2u + (m * 16 + (l & 15)) * 64 + ks * 32 + (l >> 4) * 8);
#pragma unroll
            for (int n = 0; n < 4; n++) MFMA(acc[m][n], w, B[n][ks]);
        }
    write_tiles(lds, l, acc, hb2);
    __syncthreads();

    // ---- stage 3: 64 -> 20
#pragma unroll
    for (int n = 0; n < 4; n++)
#pragma unroll
        for (int ks = 0; ks < 2; ks++) {
            int e = n * 16 + (l & 15);
            int g = ks * 4 + (l >> 4);
            B[n][ks] = *(const u4*)(lds + e * 128 + ((g ^ (e & 7)) << 4));
        }

    f4 acc3[2][4];
#pragma unroll
    for (int m = 0; m < 2; m++)
#pragma unroll
        for (int n = 0; n < 4; n++) { acc3[m][n].x = 0.f; acc3[m][n].y = 0.f; acc3[m][n].z = 0.f; acc3[m][n].w = 0.f; }
#pragma unroll
    for (int m = 0; m < 2; m++)
#pragma unroll
        for (int ks = 0; ks < 2; ks++) {
            u4 w = *(const u4*)(H3u + (m * 16 + (l & 15)) * 64 + ks * 32 + (l >> 4) * 8);
#pragma unroll
            for (int n = 0; n < 4; n++) MFMA(acc3[m][n], w, B[n][ks]);
        }

#pragma unroll
    for (int m = 0; m < 2; m++) {
#pragma unroll
        for (int j = 0; j < 4; j++) {
            int ch = m * 16 + (l >> 4) * 4 + j;
            if (ch < 20) {
                float b = hb3[ch];
#pragma unroll
                for (int nt = 0; nt < 4; nt++) {
                    int node = n0 + nt * 16 + (l & 15);
                    if (node < NN) {
                        float v = acc3[m][nt][j] + b;
                        if (ch < 2)       out[node * 2 + ch] = v;
                        else if (ch == 2) out[2 * NN + node] = v;
                        else if (ch < 19) out[3 * NN + node * 16 + (ch - 3)] = v;
                        else              out[19 * NN + node] = v;
                    }
                }
            }
        }
    }
}

// ---------------------------------------------------------------- launch
extern "C" void kernel_launch(void* const* d_in, const int* in_sizes, int n_in,
                              void* d_out, int out_size, void* d_ws, size_t ws_size,
                              hipStream_t stream)
{
    const float* x      = (const float*)d_in[0];
    const float* angle  = (const float*)d_in[1];
    const float* mol    = (const float*)d_in[2];
    const float* gen    = (const float*)d_in[3];
    const int*   src    = (const int*)d_in[4];
    const int*   dst    = (const int*)d_in[5];
    const float* mask   = (const float*)d_in[6];
    const float* mw1    = (const float*)d_in[7];
    const float* mb1    = (const float*)d_in[8];
    const float* mw2    = (const float*)d_in[9];
    const float* mb2    = (const float*)d_in[10];
    const float* mw3    = (const float*)d_in[11];
    const float* mb3    = (const float*)d_in[12];
    const float* wq     = (const float*)d_in[13];
    const float* bq     = (const float*)d_in[14];
    const float* wk     = (const float*)d_in[15];
    const float* bk     = (const float*)d_in[16];
    const float* wv     = (const float*)d_in[17];
    const float* bv     = (const float*)d_in[18];
    const float* we     = (const float*)d_in[19];
    const float* wskip  = (const float*)d_in[20];
    const float* bskip  = (const float*)d_in[21];
    const float* hw1    = (const float*)d_in[22];
    const float* hb1    = (const float*)d_in[23];
    const float* hw2    = (const float*)d_in[24];
    const float* hb2    = (const float*)d_in[25];
    const float* hw3    = (const float*)d_in[26];
    const float* hb3    = (const float*)d_in[27];
    float* out = (float*)d_out;

    char* p = (char*)d_ws;
    auto alloc = [&](size_t bytes) -> void* {
        void* r = (void*)p;
        p += (bytes + 255) & ~(size_t)255;
        return r;
    };
    int*   row_off = (int*)alloc((NN + 1) * 4);
    float* selff   = (float*)alloc((size_t)NN * 20 * 4);
    __hip_bfloat16* selffb = (__hip_bfloat16*)alloc((size_t)NN * 32 * 2);
    float* qkp     = (float*)alloc((size_t)NN * 64 * 4);
    float* skipf   = (float*)alloc((size_t)NN * 64 * 4);
    float* qwe     = (float*)alloc((size_t)NN * 168 * 4);
    __hip_bfloat16* agg = (__hip_bfloat16*)alloc((size_t)NN * 256 * 2);
    float* invp    = (float*)alloc((size_t)NN * 2 * 4);
    __hip_bfloat16* W1b = (__hip_bfloat16*)alloc(2048 * 2);
    __hip_bfloat16* W2b = (__hip_bfloat16*)alloc(4096 * 2);
    __hip_bfloat16* W3b = (__hip_bfloat16*)alloc(4096 * 2);
    __hip_bfloat16* H1b = (__hip_bfloat16*)alloc(4096 * 2);
    __hip_bfloat16* H2b = (__hip_bfloat16*)alloc(4096 * 2);
    __hip_bfloat16* H3b = (__hip_bfloat16*)alloc(2048 * 2);
    __hip_bfloat16* WcA = (__hip_bfloat16*)alloc(16384 * 2);
    float* Mwe     = (float*)alloc(3528 * 4);
    float* Mk      = (float*)alloc(1344 * 4);
    __hip_bfloat16* msg = (__hip_bfloat16*)alloc((size_t)EF * 64 * 2);

    k_prep<<<164, 256, 0, stream>>>(mw1, mb1, mw2, mw3, hw1, hw2, hw3, we, wk, bk, wv, bv,
                                    wq, bq, W1b, W2b, W3b, H1b, H2b, H3b, WcA, Mwe, Mk);
    k_csr<<<(NN + 256) / 256, 256, 0, stream>>>(dst, mask, row_off);
    k_node<<<NN / 4, 256, 0, stream>>>(angle, mol, gen, row_off,
                                       wskip, bskip, Mwe, Mk,
                                       selff, selffb, skipf, qwe, qkp);
    k_edge_mfma<<<(EF / 64 + 3) / 4, 256, 0, stream>>>(x, angle, mol, src, dst,
                                                       W1b, W2b, W3b, mb2, mb3, msg);
    k_attn<<<NN / 4, 256, 0, stream>>>(row_off, src, msg, selffb, qkp,
                                       qwe, selff, agg, invp);
    k_final2<<<(NN + 63) / 64, 64, 0, stream>>>(agg, invp, skipf, WcA,
                                                H1b, H2b, H3b, hb1, hb2, hb3, out);
}

// Round 11
// 145.972 us; speedup vs baseline: 1.5022x; 1.0457x over previous
//
#include <hip/hip_runtime.h>
#include <hip/hip_bf16.h>
#include <math.h>

#define NN 20000
#define EF 720000

typedef float  f4 __attribute__((ext_vector_type(4)));
typedef unsigned int u4 __attribute__((ext_vector_type(4)));

__device__ __forceinline__ void MFMA(f4& c, u4 a, u4 b) {
    asm("v_mfma_f32_16x16x32_bf16 %0, %1, %2, %0" : "+v"(c) : "v"(a), "v"(b));
}

__device__ __forceinline__ unsigned pk(float a, float b) {
    __hip_bfloat162 t = __halves2bfloat162(__float2bfloat16(a), __float2bfloat16(b));
    unsigned u; __builtin_memcpy(&u, &t, 4); return u;
}
__device__ __forceinline__ float bf2f(unsigned short u) {
    return __builtin_bit_cast(float, (unsigned)u << 16);
}
__device__ __forceinline__ f4 bf2f4(ushort4 u) {
    f4 r; r.x = bf2f(u.x); r.y = bf2f(u.y); r.z = bf2f(u.z); r.w = bf2f(u.w); return r;
}
__device__ __forceinline__ float dot4(f4 a, f4 b) {
    return a.x * b.x + a.y * b.y + a.z * b.z + a.w * b.w;
}
__device__ __forceinline__ void fma4(f4& acc, float w, f4 v) {
    acc.x += w * v.x; acc.y += w * v.y; acc.z += w * v.z; acc.w += w * v.w;
}

// ---------------------------------------------------------------- prep: bf16 weights + composed projections
__global__ __launch_bounds__(256) void k_prep(
    const float* __restrict__ mw1, const float* __restrict__ mb1,
    const float* __restrict__ mw2, const float* __restrict__ mw3,
    const float* __restrict__ hw1, const float* __restrict__ hw2, const float* __restrict__ hw3,
    const float* __restrict__ we, const float* __restrict__ wk, const float* __restrict__ bk,
    const float* __restrict__ wv, const float* __restrict__ bv,
    const float* __restrict__ wq, const float* __restrict__ bq,
    __hip_bfloat16* __restrict__ W1b, __hip_bfloat16* __restrict__ W2b, __hip_bfloat16* __restrict__ W3b,
    __hip_bfloat16* __restrict__ H1b, __hip_bfloat16* __restrict__ H2b, __hip_bfloat16* __restrict__ H3b,
    __hip_bfloat16* __restrict__ WcA, float* __restrict__ Mwe, float* __restrict__ Mk)
{
    int t = blockIdx.x * 256 + threadIdx.x;
    if (t < 2048) {  // W1b[ch][k], K=32: k<21 weights, k==21 bias, rest 0
        int ch = t >> 5, k = t & 31;
        float v = (k < 21) ? mw1[k * 64 + ch] : (k == 21 ? mb1[ch] : 0.f);
        W1b[t] = __float2bfloat16(v); return;
    }
    t -= 2048;
    if (t < 4096) { int ch = t >> 6, k = t & 63; W2b[t] = __float2bfloat16(mw2[k * 64 + ch]); return; }
    t -= 4096;
    if (t < 4096) { int ch = t >> 6, k = t & 63; W3b[t] = __float2bfloat16(mw3[k * 64 + ch]); return; }
    t -= 4096;
    if (t < 4096) { int ch = t >> 6, k = t & 63; H1b[t] = __float2bfloat16(hw1[k * 64 + ch]); return; }
    t -= 4096;
    if (t < 4096) { int ch = t >> 6, k = t & 63; H2b[t] = __float2bfloat16(hw2[k * 64 + ch]); return; }
    t -= 4096;
    if (t < 2048) {  // H3b padded to 32 rows
        int ch = t >> 6, k = t & 63;
        float v = (ch < 20) ? hw3[k * 20 + ch] : 0.f;
        H3b[t] = __float2bfloat16(v); return;
    }
    t -= 2048;
    if (t < 16384) {
        int h = t >> 13, rem = t & 8191;
        int ch = rem >> 7, k = rem & 127;
        int col = h * 64 + ch;
        float v;
        if (k < 64)        v = we[k * 128 + col];
        else if (k < 84)   v = wv[(k - 64) * 128 + col];
        else if (k == 84)  v = bv[col];
        else if (k < 96)   v = 0.f;
        else if (k < 116)  v = we[(64 + (k - 96)) * 128 + col];
        else               v = 0.f;
        WcA[t] = __float2bfloat16(v); return;
    }
    t -= 16384;
    if (t < 3528) {  // Mwe: 21 x 168
        int j = t / 168, o = t % 168;
        int h = (o >= 84) ? 1 : 0, a = o - 84 * h;
        float acc = 0.f;
        for (int c = 0; c < 64; c++) {
            int hc = h * 64 + c;
            float wqv = (j < 20) ? wq[j * 128 + hc] : bq[hc];
            acc += wqv * we[a * 128 + hc];
        }
        Mwe[t] = acc; return;
    }
    t -= 3528;
    if (t < 1344) {  // Mk: 21 x 64
        int j = t / 64, rem = t % 64;
        int h = rem >> 5, a = rem & 31;
        float acc = 0.f;
        if (a <= 20) {
            for (int c = 0; c < 64; c++) {
                int hc = h * 64 + c;
                float wqv = (j < 20) ? wq[j * 128 + hc] : bq[hc];
                float wkv = (a < 20) ? wk[a * 128 + hc] : bk[hc];
                acc += wqv * wkv;
            }
        }
        Mk[t] = acc; return;
    }
}

// ---------------------------------------------------------------- CSR via binary search
__global__ __launch_bounds__(256) void k_csr(
    const int* __restrict__ dst, const float* __restrict__ mask, int* __restrict__ row_off)
{
    int n = blockIdx.x * 256 + threadIdx.x;
    if (n > NN) return;
    int lo = 0, hi = EF;
    while (lo < hi) { int mid = (lo + hi) >> 1; if (mask[mid] > 0.5f) lo = mid + 1; else hi = mid; }
    int Ea = lo;
    lo = 0; hi = Ea;
    while (lo < hi) { int mid = (lo + hi) >> 1; if (dst[mid] < n) lo = mid + 1; else hi = mid; }
    row_off[n] = lo;
}

// ---------------------------------------------------------------- node features + composed projections (L1-hot tables)
__global__ __launch_bounds__(256) void k_node(
    const float* __restrict__ angle, const float* __restrict__ mol, const float* __restrict__ gen,
    const int* __restrict__ row_off,
    const float* __restrict__ wskip, const float* __restrict__ bskip,
    const float* __restrict__ Mwe, const float* __restrict__ Mk,
    float* __restrict__ selff, __hip_bfloat16* __restrict__ selffb,
    float* __restrict__ skipf, float* __restrict__ qwe, float* __restrict__ qkp)
{
    int wid = threadIdx.x >> 6, lane = threadIdx.x & 63;
    int n = blockIdx.x * 4 + wid;

    float an = angle[n];
    float sv, cv; sincosf(an, &sv, &cv);
    float degf = (float)(row_off[n + 1] - row_off[n]);
    float sfa[21];
    sfa[0] = sv; sfa[1] = cv;
#pragma unroll
    for (int j = 0; j < 16; j++) sfa[2 + j] = mol[n * 16 + j];
    sfa[18] = gen[n];
    sfa[19] = degf;
    sfa[20] = 1.f;

    float sval = (lane == 0) ? sv : (lane == 1) ? cv :
                 (lane < 18) ? mol[n * 16 + (lane - 2)] :
                 (lane == 18) ? gen[n] : degf;
    if (lane < 20) selff[n * 20 + lane] = sval;
    if (lane < 32) {
        float v = (lane < 20) ? sval : (lane == 20 ? 1.f : 0.f);
        selffb[n * 32 + lane] = __float2bfloat16(v);
    }

    float sk = bskip[lane];
#pragma unroll
    for (int j = 0; j < 20; j++) sk += sfa[j] * wskip[j * 64 + lane];
    skipf[n * 64 + lane] = sk;

#pragma unroll
    for (int r = 0; r < 3; r++) {
        int o = r * 64 + lane;
        if (o < 168) {
            float acc = 0.f;
#pragma unroll
            for (int j = 0; j < 21; j++) acc += sfa[j] * Mwe[j * 168 + o];
            qwe[n * 168 + o] = acc;
        }
    }

    {
        float acc = 0.f;
#pragma unroll
        for (int j = 0; j < 21; j++) acc += sfa[j] * Mk[j * 64 + lane];
        qkp[n * 64 + lane] = acc;
    }
}

// ---------------------------------------------------------------- edge MLP via MFMA (wave = 64 edges, 4 waves/block)
// Per-wave PRIVATE LDS slice -> NO __syncthreads needed: same-wave LDS
// write->read ordering is guaranteed by compiler-inserted lgkmcnt waits
// (validated pattern, k_attn r2-r10). Waves run unsynced for latency hiding.
__device__ __forceinline__ void write_tiles(char* lds, int l, f4 (&acc)[4][4], const float* bias)
{
#pragma unroll
    for (int m = 0; m < 4; m++) {
        f4 bv;
        if (bias) bv = *(const f4*)(bias + m * 16 + ((l >> 4) << 2));
        else      { bv.x = 0.f; bv.y = 0.f; bv.z = 0.f; bv.w = 0.f; }
#pragma unroll
        for (int n = 0; n < 4; n++) {
            f4 v = acc[m][n];
            float v0 = fmaxf(v.x + bv.x, 0.f);
            float v1 = fmaxf(v.y + bv.y, 0.f);
            float v2 = fmaxf(v.z + bv.z, 0.f);
            float v3 = fmaxf(v.w + bv.w, 0.f);
            int e   = n * 16 + (l & 15);
            int ch0 = m * 16 + ((l >> 4) << 2);
            int byte = e * 128 + ((((ch0 >> 3) ^ (e & 7))) << 4) + (ch0 & 7) * 2;
            uint2 w; w.x = pk(v0, v1); w.y = pk(v2, v3);
            *(uint2*)(lds + byte) = w;
        }
    }
}

__global__ __launch_bounds__(256) void k_edge_mfma(
    const float* __restrict__ x, const float* __restrict__ angle, const float* __restrict__ mol,
    const int* __restrict__ src, const int* __restrict__ dst,
    const float* __restrict__ mask,
    const __hip_bfloat16* __restrict__ W1b, const __hip_bfloat16* __restrict__ W2b,
    const __hip_bfloat16* __restrict__ W3b,
    const float* __restrict__ mb2, const float* __restrict__ mb3,
    __hip_bfloat16* __restrict__ msg)
{
    __shared__ char lds_all[4][64 * 128];
    int wv = threadIdx.x >> 6, l = threadIdx.x & 63;
    char* lds = lds_all[wv];
    int e0 = (blockIdx.x * 4 + wv) * 64;
    if (e0 + 64 > EF) e0 = EF - 64;

    // mask is a prefix: if this tile's first edge is padded, the whole tile is
    // padded and its msg rows are never read (row_off caps at Ea). Skip.
    if (mask[e0] < 0.5f) return;

    int s = src[e0 + l], d = dst[e0 + l];
    float2 xs = ((const float2*)x)[s], xd = ((const float2*)x)[d];
    float dx = xs.x - xd.x, dy = xs.y - xd.y;
    float r = sqrtf(fmaxf(dx * dx + dy * dy, 1e-12f));
    float da = angle[s] - angle[d];
    float sv, cv; sincosf(da, &sv, &cv);
    const float4* m4 = (const float4*)mol;
    float4 sa = m4[s * 4 + 0], sb = m4[s * 4 + 1], sc = m4[s * 4 + 2], sd = m4[s * 4 + 3];
    float4 ta = m4[d * 4 + 0], tb = m4[d * 4 + 1], tc = m4[d * 4 + 2], td = m4[d * 4 + 3];
    float f[22];
    f[0] = dx; f[1] = dy; f[2] = r; f[3] = sv; f[4] = cv;
    f[5]  = sa.x - ta.x; f[6]  = sa.y - ta.y; f[7]  = sa.z - ta.z; f[8]  = sa.w - ta.w;
    f[9]  = sb.x - tb.x; f[10] = sb.y - tb.y; f[11] = sb.z - tb.z; f[12] = sb.w - tb.w;
    f[13] = sc.x - tc.x; f[14] = sc.y - tc.y; f[15] = sc.z - tc.z; f[16] = sc.w - tc.w;
    f[17] = sd.x - td.x; f[18] = sd.y - td.y; f[19] = sd.z - td.z; f[20] = sd.w - td.w;
    f[21] = 1.f;
    unsigned p[16];
#pragma unroll
    for (int j = 0; j < 11; j++) p[j] = pk(f[2 * j], f[2 * j + 1]);
#pragma unroll
    for (int j = 11; j < 16; j++) p[j] = 0u;
#pragma unroll
    for (int g = 0; g < 4; g++) {
        int byte = l * 64 + ((g ^ (l & 3)) << 4);
        u4 w; w.x = p[4 * g]; w.y = p[4 * g + 1]; w.z = p[4 * g + 2]; w.w = p[4 * g + 3];
        *(u4*)(lds + byte) = w;
    }

    u4 B1[4];
#pragma unroll
    for (int n = 0; n < 4; n++) {
        int e = n * 16 + (l & 15);
        int byte = e * 64 + ((((l >> 4) & 3) ^ (e & 3)) << 4);
        B1[n] = *(const u4*)(lds + byte);
    }

    f4 acc[4][4];
#pragma unroll
    for (int m = 0; m < 4; m++)
#pragma unroll
        for (int n = 0; n < 4; n++) { acc[m][n].x = 0.f; acc[m][n].y = 0.f; acc[m][n].z = 0.f; acc[m][n].w = 0.f; }

    const unsigned short* W1u = (const unsigned short*)W1b;
    const unsigned short* W2u = (const unsigned short*)W2b;
    const unsigned short* W3u = (const unsigned short*)W3b;
#pragma unroll
    for (int m = 0; m < 4; m++) {
        u4 w = *(const u4*)(W1u + (m * 16 + (l & 15)) * 32 + (l >> 4) * 8);
#pragma unroll
        for (int n = 0; n < 4; n++) MFMA(acc[m][n], w, B1[n]);
    }
    write_tiles(lds, l, acc, nullptr);

    u4 B2[4][2];
#pragma unroll
    for (int n = 0; n < 4; n++)
#pragma unroll
        for (int ks = 0; ks < 2; ks++) {
            int e = n * 16 + (l & 15);
            int g = ks * 4 + (l >> 4);
            B2[n][ks] = *(const u4*)(lds + e * 128 + ((g ^ (e & 7)) << 4));
        }
#pragma unroll
    for (int m = 0; m < 4; m++)
#pragma unroll
        for (int n = 0; n < 4; n++) { acc[m][n].x = 0.f; acc[m][n].y = 0.f; acc[m][n].z = 0.f; acc[m][n].w = 0.f; }
#pragma unroll
    for (int m = 0; m < 4; m++)
#pragma unroll
        for (int ks = 0; ks < 2; ks++) {
            u4 w = *(const u4*)(W2u + (m * 16 + (l & 15)) * 64 + ks * 32 + (l >> 4) * 8);
#pragma unroll
            for (int n = 0; n < 4; n++) MFMA(acc[m][n], w, B2[n][ks]);
        }
    write_tiles(lds, l, acc, mb2);

#pragma unroll
    for (int n = 0; n < 4; n++)
#pragma unroll
        for (int ks = 0; ks < 2; ks++) {
            int e = n * 16 + (l & 15);
            int g = ks * 4 + (l >> 4);
            B2[n][ks] = *(const u4*)(lds + e * 128 + ((g ^ (e & 7)) << 4));
        }
#pragma unroll
    for (int m = 0; m < 4; m++)
#pragma unroll
        for (int n = 0; n < 4; n++) { acc[m][n].x = 0.f; acc[m][n].y = 0.f; acc[m][n].z = 0.f; acc[m][n].w = 0.f; }
#pragma unroll
    for (int m = 0; m < 4; m++)
#pragma unroll
        for (int ks = 0; ks < 2; ks++) {
            u4 w = *(const u4*)(W3u + (m * 16 + (l & 15)) * 64 + ks * 32 + (l >> 4) * 8);
#pragma unroll
            for (int n = 0; n < 4; n++) MFMA(acc[m][n], w, B2[n][ks]);
        }
    write_tiles(lds, l, acc, mb3);

#pragma unroll
    for (int it = 0; it < 8; it++) {
        int e = it * 8 + (l >> 3);
        int g = l & 7;
        u4 vv = *(const u4*)(lds + e * 128 + ((g ^ (e & 7)) << 4));
        *(u4*)((unsigned short*)msg + (size_t)(e0 + e) * 64 + g * 8) = vv;
    }
}

// ---------------------------------------------------------------- attention aggregate (edge loop only)
// agg[n][256] bf16 per head h (base h*128): [0..63]=Wm_h, [64..95]=Ws_h (a=0..31, slot 20 = S_h),
// [96..127]=S_h*sf (20 real + 12 zero). invp[n][2] = 1/(S_h+1e-16).
__global__ __launch_bounds__(256) void k_attn(
    const int* __restrict__ row_off, const int* __restrict__ src,
    const __hip_bfloat16* __restrict__ msg,
    const __hip_bfloat16* __restrict__ selffb, const float* __restrict__ qkp,
    const float* __restrict__ qwe, const float* __restrict__ selff,
    __hip_bfloat16* __restrict__ agg, float* __restrict__ invp)
{
    int tid = threadIdx.x, wid = tid >> 6, lane = tid & 63;
    int g = lane >> 4, c16 = lane & 15;
    int n = blockIdx.x * 4 + wid;

    f4 qm0 = *(const f4*)(qwe + n * 168 + 4 * c16);
    f4 qm1 = *(const f4*)(qwe + n * 168 + 84 + 4 * c16);
    float2 qk0 = *(const float2*)(qkp + n * 64 + 2 * c16);
    float2 qk1 = *(const float2*)(qkp + n * 64 + 32 + 2 * c16);

    float a00 = 0.f, a01 = 0.f;
#pragma unroll
    for (int j = 0; j < 20; j++) {
        float sfj = selff[n * 20 + j];
        a00 += sfj * qwe[n * 168 + 64 + j];
        a01 += sfj * qwe[n * 168 + 84 + 64 + j];
    }

    const unsigned short* msgu = (const unsigned short*)msg;
    const unsigned short* sfu  = (const unsigned short*)selffb;
    int r0 = row_off[n], r1 = row_off[n + 1];
    int nit = (r1 - r0 + 3) >> 2;

    f4 Wm0 = {0,0,0,0}, Wm1 = {0,0,0,0};
    float Ws00 = 0.f, Ws01 = 0.f, Ws10 = 0.f, Ws11 = 0.f;
    float S0 = 0.f, S1 = 0.f;

#pragma unroll 2
    for (int it = 0; it < nit; it++) {
        int e = r0 + it * 4 + g;
        bool ok = (e < r1);
        int ec = ok ? e : r0;
        int s = src[ec];
        ushort2 su = *(const ushort2*)(sfu + (size_t)s * 32 + 2 * c16);
        float sf0 = bf2f(su.x), sf1 = bf2f(su.y);
        f4 mc = bf2f4(*(const ushort4*)(msgu + (size_t)ec * 64 + 4 * c16));

        float t0 = dot4(qm0, mc) + sf0 * qk0.x + sf1 * qk0.y;
        float t1 = dot4(qm1, mc) + sf0 * qk1.x + sf1 * qk1.y;
#pragma unroll
        for (int mk = 1; mk < 16; mk <<= 1) {
            t0 += __shfl_xor(t0, mk, 64);
            t1 += __shfl_xor(t1, mk, 64);
        }
        float w0 = ok ? __expf((t0 + a00) * 0.125f) : 0.f;
        float w1 = ok ? __expf((t1 + a01) * 0.125f) : 0.f;
        S0 += w0; S1 += w1;
        fma4(Wm0, w0, mc); fma4(Wm1, w1, mc);
        Ws00 += w0 * sf0; Ws01 += w0 * sf1;
        Ws10 += w1 * sf0; Ws11 += w1 * sf1;
    }

    // cross-group butterfly: every lane ends with full-node totals for its channel slice
#pragma unroll
    for (int mk = 16; mk <= 32; mk <<= 1) {
        Wm0.x += __shfl_xor(Wm0.x, mk, 64); Wm0.y += __shfl_xor(Wm0.y, mk, 64);
        Wm0.z += __shfl_xor(Wm0.z, mk, 64); Wm0.w += __shfl_xor(Wm0.w, mk, 64);
        Wm1.x += __shfl_xor(Wm1.x, mk, 64); Wm1.y += __shfl_xor(Wm1.y, mk, 64);
        Wm1.z += __shfl_xor(Wm1.z, mk, 64); Wm1.w += __shfl_xor(Wm1.w, mk, 64);
        Ws00 += __shfl_xor(Ws00, mk, 64); Ws01 += __shfl_xor(Ws01, mk, 64);
        Ws10 += __shfl_xor(Ws10, mk, 64); Ws11 += __shfl_xor(Ws11, mk, 64);
        S0 += __shfl_xor(S0, mk, 64); S1 += __shfl_xor(S1, mk, 64);
    }

    unsigned short* arow = (unsigned short*)agg + (size_t)n * 256;
    if (g == 0) {
        uint2 w; w.x = pk(Wm0.x, Wm0.y); w.y = pk(Wm0.z, Wm0.w);
        *(uint2*)(arow + 4 * c16) = w;
        int j0 = 2 * c16, j1 = 2 * c16 + 1;
        float v0 = (j0 < 20) ? S0 * selff[n * 20 + j0] : 0.f;
        float v1 = (j1 < 20) ? S0 * selff[n * 20 + j1] : 0.f;
        *(unsigned*)(arow + 96 + 2 * c16) = pk(v0, v1);
    } else if (g == 1) {
        uint2 w; w.x = pk(Wm1.x, Wm1.y); w.y = pk(Wm1.z, Wm1.w);
        *(uint2*)(arow + 128 + 4 * c16) = w;
        int j0 = 2 * c16, j1 = 2 * c16 + 1;
        float v0 = (j0 < 20) ? S1 * selff[n * 20 + j0] : 0.f;
        float v1 = (j1 < 20) ? S1 * selff[n * 20 + j1] : 0.f;
        *(unsigned*)(arow + 128 + 96 + 2 * c16) = pk(v0, v1);
    } else if (g == 2) {
        *(unsigned*)(arow + 64 + 2 * c16) = pk(Ws00, Ws01);
        if (c16 == 0) invp[2 * n] = 1.f / (S0 + 1e-16f);
    } else {
        *(unsigned*)(arow + 128 + 64 + 2 * c16) = pk(Ws10, Ws11);
        if (c16 == 0) invp[2 * n + 1] = 1.f / (S1 + 1e-16f);
    }
}

// ---------------------------------------------------------------- fused attn-epilogue + final MLP (1 wave = 64 nodes)
__global__ __launch_bounds__(64) void k_final2(
    const __hip_bfloat16* __restrict__ agg, const float* __restrict__ invp,
    const float* __restrict__ skipf, const __hip_bfloat16* __restrict__ WcA,
    const __hip_bfloat16* __restrict__ H1b, const __hip_bfloat16* __restrict__ H2b,
    const __hip_bfloat16* __restrict__ H3b,
    const float* __restrict__ hb1, const float* __restrict__ hb2, const float* __restrict__ hb3,
    float* __restrict__ out)
{
    __shared__ char lds[64 * 128];
    int l = threadIdx.x;
    int n0 = blockIdx.x * 64;

    const unsigned short* aggU = (const unsigned short*)agg;
    const unsigned short* WcU = (const unsigned short*)WcA;
    const unsigned short* H1u = (const unsigned short*)H1b;
    const unsigned short* H2u = (const unsigned short*)H2b;
    const unsigned short* H3u = (const unsigned short*)H3b;

    int nodes[4];
    float inv0[4], inv1[4];
#pragma unroll
    for (int n4 = 0; n4 < 4; n4++) {
        int node = n0 + n4 * 16 + (l & 15); if (node >= NN) node = NN - 1;
        nodes[n4] = node;
        float2 iv = *(const float2*)(invp + 2 * node);
        inv0[n4] = iv.x; inv1[n4] = iv.y;
    }

    f4 osum[4][4];
#pragma unroll
    for (int m = 0; m < 4; m++)
#pragma unroll
        for (int n4 = 0; n4 < 4; n4++) { osum[m][n4].x = 0.f; osum[m][n4].y = 0.f; osum[m][n4].z = 0.f; osum[m][n4].w = 0.f; }

    // stage 0: per head, K=128 GEMM  D[ch][node] = Wc_h @ agg_h  (B from global)
#pragma unroll
    for (int h = 0; h < 2; h++) {
        f4 acc[4][4];
#pragma unroll
        for (int m = 0; m < 4; m++)
#pragma unroll
            for (int n4 = 0; n4 < 4; n4++) { acc[m][n4].x = 0.f; acc[m][n4].y = 0.f; acc[m][n4].z = 0.f; acc[m][n4].w = 0.f; }
#pragma unroll
        for (int ks = 0; ks < 4; ks++) {
            u4 A[4];
#pragma unroll
            for (int m = 0; m < 4; m++)
                A[m] = *(const u4*)(WcU + h * 8192 + (m * 16 + (l & 15)) * 128 + ks * 32 + (l >> 4) * 8);
#pragma unroll
            for (int n4 = 0; n4 < 4; n4++) {
                u4 B = *(const u4*)(aggU + (size_t)nodes[n4] * 256 + h * 128 + ks * 32 + (l >> 4) * 8);
#pragma unroll
                for (int m = 0; m < 4; m++) MFMA(acc[m][n4], A[m], B);
            }
        }
        const float* iv = h ? inv1 : inv0;
#pragma unroll
        for (int m = 0; m < 4; m++)
#pragma unroll
            for (int n4 = 0; n4 < 4; n4++) fma4(osum[m][n4], 0.5f * iv[n4], acc[m][n4]);
    }

    // add skip, pack into [64 nodes][64 ch] bf16 LDS tile
#pragma unroll
    for (int m = 0; m < 4; m++) {
#pragma unroll
        for (int n4 = 0; n4 < 4; n4++) {
            int ch0 = m * 16 + ((l >> 4) << 2);
            float4 sk = *(const float4*)(skipf + (size_t)nodes[n4] * 64 + ch0);
            f4 v = osum[m][n4];
            float v0 = v.x + sk.x, v1 = v.y + sk.y, v2 = v.z + sk.z, v3 = v.w + sk.w;
            int e = n4 * 16 + (l & 15);
            int byte = e * 128 + ((((ch0 >> 3) ^ (e & 7))) << 4) + (ch0 & 7) * 2;
            uint2 w; w.x = pk(v0, v1); w.y = pk(v2, v3);
            *(uint2*)(lds + byte) = w;
        }
    }
    __syncthreads();

    u4 B[4][2];
    f4 acc[4][4];

    // ---- stage 1
#pragma unroll
    for (int n = 0; n < 4; n++)
#pragma unroll
        for (int ks = 0; ks < 2; ks++) {
            int e = n * 16 + (l & 15);
            int g = ks * 4 + (l >> 4);
            B[n][ks] = *(const u4*)(lds + e * 128 + ((g ^ (e & 7)) << 4));
        }
    __syncthreads();
#pragma unroll
    for (int m = 0; m < 4; m++)
#pragma unroll
        for (int n = 0; n < 4; n++) { acc[m][n].x = 0.f; acc[m][n].y = 0.f; acc[m][n].z = 0.f; acc[m][n].w = 0.f; }
#pragma unroll
    for (int m = 0; m < 4; m++)
#pragma unroll
        for (int ks = 0; ks < 2; ks++) {
            u4 w = *(const u4*)(H1u + (m * 16 + (l & 15)) * 64 + ks * 32 + (l >> 4) * 8);
#pragma unroll
            for (int n = 0; n < 4; n++) MFMA(acc[m][n], w, B[n][ks]);
        }
    write_tiles(lds, l, acc, hb1);
    __syncthreads();

    // ---- stage 2
#pragma unroll
    for (int n = 0; n < 4; n++)
#pragma unroll
        for (int ks = 0; ks < 2; ks++) {
            int e = n * 16 + (l & 15);
            int g = ks * 4 + (l >> 4);
            B[n][ks] = *(const u4*)(lds + e * 128 + ((g ^ (e & 7)) << 4));
        }
    __syncthreads();
#pragma unroll
    for (int m = 0; m < 4; m++)
#pragma unroll
        for (int n = 0; n < 4; n++) { acc[m][n].x = 0.f; acc[m][n].y = 0.f; acc[m][n].z = 0.f; acc[m][n].w = 0.f; }
#pragma unroll
    for (int m = 0; m < 4; m++)
#pragma unroll
        for (int ks = 0; ks < 2; ks++) {
            u4 w = *(const u4*)(H2u + (m * 16 + (l & 15)) * 64 + ks * 32 + (l >> 4) * 8);
#pragma unroll
            for (int n = 0; n < 4; n++) MFMA(acc[m][n], w, B[n][ks]);
        }
    write_tiles(lds, l, acc, hb2);
    __syncthreads();

    // ---- stage 3: 64 -> 20
#pragma unroll
    for (int n = 0; n < 4; n++)
#pragma unroll
        for (int ks = 0; ks < 2; ks++) {
            int e = n * 16 + (l & 15);
            int g = ks * 4 + (l >> 4);
            B[n][ks] = *(const u4*)(lds + e * 128 + ((g ^ (e & 7)) << 4));
        }

    f4 acc3[2][4];
#pragma unroll
    for (int m = 0; m < 2; m++)
#pragma unroll
        for (int n = 0; n < 4; n++) { acc3[m][n].x = 0.f; acc3[m][n].y = 0.f; acc3[m][n].z = 0.f; acc3[m][n].w = 0.f; }
#pragma unroll
    for (int m = 0; m < 2; m++)
#pragma unroll
        for (int ks = 0; ks < 2; ks++) {
            u4 w = *(const u4*)(H3u + (m * 16 + (l & 15)) * 64 + ks * 32 + (l >> 4) * 8);
#pragma unroll
            for (int n = 0; n < 4; n++) MFMA(acc3[m][n], w, B[n][ks]);
        }

#pragma unroll
    for (int m = 0; m < 2; m++) {
#pragma unroll
        for (int j = 0; j < 4; j++) {
            int ch = m * 16 + (l >> 4) * 4 + j;
            if (ch < 20) {
                float b = hb3[ch];
#pragma unroll
                for (int nt = 0; nt < 4; nt++) {
                    int node = n0 + nt * 16 + (l & 15);
                    if (node < NN) {
                        float v = acc3[m][nt][j] + b;
                        if (ch < 2)       out[node * 2 + ch] = v;
                        else if (ch == 2) out[2 * NN + node] = v;
                        else if (ch < 19) out[3 * NN + node * 16 + (ch - 3)] = v;
                        else              out[19 * NN + node] = v;
                    }
                }
            }
        }
    }
}

// ---------------------------------------------------------------- launch
extern "C" void kernel_launch(void* const* d_in, const int* in_sizes, int n_in,
                              void* d_out, int out_size, void* d_ws, size_t ws_size,
                              hipStream_t stream)
{
    const float* x      = (const float*)d_in[0];
    const float* angle  = (const float*)d_in[1];
    const float* mol    = (const float*)d_in[2];
    const float* gen    = (const float*)d_in[3];
    const int*   src    = (const int*)d_in[4];
    const int*   dst    = (const int*)d_in[5];
    const float* mask   = (const float*)d_in[6];
    const float* mw1    = (const float*)d_in[7];
    const float* mb1    = (const float*)d_in[8];
    const float* mw2    = (const float*)d_in[9];
    const float* mb2    = (const float*)d_in[10];
    const float* mw3    = (const float*)d_in[11];
    const float* mb3    = (const float*)d_in[12];
    const float* wq     = (const float*)d_in[13];
    const float* bq     = (const float*)d_in[14];
    const float* wk     = (const float*)d_in[15];
    const float* bk     = (const float*)d_in[16];
    const float* wv     = (const float*)d_in[17];
    const float* bv     = (const float*)d_in[18];
    const float* we     = (const float*)d_in[19];
    const float* wskip  = (const float*)d_in[20];
    const float* bskip  = (const float*)d_in[21];
    const float* hw1    = (const float*)d_in[22];
    const float* hb1    = (const float*)d_in[23];
    const float* hw2    = (const float*)d_in[24];
    const float* hb2    = (const float*)d_in[25];
    const float* hw3    = (const float*)d_in[26];
    const float* hb3    = (const float*)d_in[27];
    float* out = (float*)d_out;

    char* p = (char*)d_ws;
    auto alloc = [&](size_t bytes) -> void* {
        void* r = (void*)p;
        p += (bytes + 255) & ~(size_t)255;
        return r;
    };
    int*   row_off = (int*)alloc((NN + 1) * 4);
    float* selff   = (float*)alloc((size_t)NN * 20 * 4);
    __hip_bfloat16* selffb = (__hip_bfloat16*)alloc((size_t)NN * 32 * 2);
    float* qkp     = (float*)alloc((size_t)NN * 64 * 4);
    float* skipf   = (float*)alloc((size_t)NN * 64 * 4);
    float* qwe     = (float*)alloc((size_t)NN * 168 * 4);
    __hip_bfloat16* agg = (__hip_bfloat16*)alloc((size_t)NN * 256 * 2);
    float* invp    = (float*)alloc((size_t)NN * 2 * 4);
    __hip_bfloat16* W1b = (__hip_bfloat16*)alloc(2048 * 2);
    __hip_bfloat16* W2b = (__hip_bfloat16*)alloc(4096 * 2);
    __hip_bfloat16* W3b = (__hip_bfloat16*)alloc(4096 * 2);
    __hip_bfloat16* H1b = (__hip_bfloat16*)alloc(4096 * 2);
    __hip_bfloat16* H2b = (__hip_bfloat16*)alloc(4096 * 2);
    __hip_bfloat16* H3b = (__hip_bfloat16*)alloc(2048 * 2);
    __hip_bfloat16* WcA = (__hip_bfloat16*)alloc(16384 * 2);
    float* Mwe     = (float*)alloc(3528 * 4);
    float* Mk      = (float*)alloc(1344 * 4);
    __hip_bfloat16* msg = (__hip_bfloat16*)alloc((size_t)EF * 64 * 2);

    k_prep<<<164, 256, 0, stream>>>(mw1, mb1, mw2, mw3, hw1, hw2, hw3, we, wk, bk, wv, bv,
                                    wq, bq, W1b, W2b, W3b, H1b, H2b, H3b, WcA, Mwe, Mk);
    k_csr<<<(NN + 256) / 256, 256, 0, stream>>>(dst, mask, row_off);
    k_node<<<NN / 4, 256, 0, stream>>>(angle, mol, gen, row_off,
                                       wskip, bskip, Mwe, Mk,
                                       selff, selffb, skipf, qwe, qkp);
    k_edge_mfma<<<(EF / 64 + 3) / 4, 256, 0, stream>>>(x, angle, mol, src, dst, mask,
                                                       W1b, W2b, W3b, mb2, mb3, msg);
    k_attn<<<NN / 4, 256, 0, stream>>>(row_off, src, msg, selffb, qkp,
                                       qwe, selff, agg, invp);
    k_final2<<<(NN + 63) / 64, 64, 0, stream>>>(agg, invp, skipf, WcA,
                                                H1b, H2b, H3b, hb1, hb2, hb3, out);
}